// Round 1
// baseline (1619.265 us; speedup 1.0000x reference)
//
#include <hip/hip_runtime.h>
#include <cstdint>
#include <cstddef>

#define BATCH 256
#define DIM   512
#define HIDN  2048
#define SLOTS 32768

// ---------------------------------------------------------------------------
// Generic tiled fp32 GEMM: C[M,N] = act(A @ B^T + bias), A[M,K], B[N,K]
// M%64==0, N%64==0, K%16==0. Tile 64x64, TK=16, 256 threads, 4x4 acc/thread.
// ---------------------------------------------------------------------------
__global__ __launch_bounds__(256) void gemm_bt(
    const float* __restrict__ A, const float* __restrict__ B,
    const float* __restrict__ bias, float* __restrict__ C,
    int M, int N, int K, int relu)
{
  __shared__ __align__(16) float As[16][68];
  __shared__ __align__(16) float Bs[16][68];
  const int m0 = blockIdx.x * 64;
  const int n0 = blockIdx.y * 64;
  const int t  = threadIdx.x;
  const int tx = t & 15, ty = t >> 4;
  const int lr = t >> 2;          // 0..63
  const int lc = (t & 3) * 4;     // 0,4,8,12
  float acc[4][4] = {};
  for (int k0 = 0; k0 < K; k0 += 16) {
    float4 a = *(const float4*)(A + (size_t)(m0 + lr) * K + k0 + lc);
    float4 b = *(const float4*)(B + (size_t)(n0 + lr) * K + k0 + lc);
    __syncthreads();
    As[lc+0][lr] = a.x; As[lc+1][lr] = a.y; As[lc+2][lr] = a.z; As[lc+3][lr] = a.w;
    Bs[lc+0][lr] = b.x; Bs[lc+1][lr] = b.y; Bs[lc+2][lr] = b.z; Bs[lc+3][lr] = b.w;
    __syncthreads();
    #pragma unroll
    for (int k = 0; k < 16; ++k) {
      const float4 a4 = *(const float4*)&As[k][ty*4];
      const float4 b4 = *(const float4*)&Bs[k][tx*4];
      const float aa[4] = {a4.x, a4.y, a4.z, a4.w};
      const float bb[4] = {b4.x, b4.y, b4.z, b4.w};
      #pragma unroll
      for (int u = 0; u < 4; ++u)
        #pragma unroll
        for (int v = 0; v < 4; ++v)
          acc[u][v] = fmaf(aa[u], bb[v], acc[u][v]);
    }
  }
  #pragma unroll
  for (int u = 0; u < 4; ++u) {
    const int m = m0 + ty*4 + u;
    float o[4];
    #pragma unroll
    for (int v = 0; v < 4; ++v) {
      float c = acc[u][v];
      if (bias) c += bias[n0 + tx*4 + v];
      if (relu) c = fmaxf(c, 0.0f);
      o[v] = c;
    }
    *(float4*)(C + (size_t)m * N + n0 + tx*4) = make_float4(o[0], o[1], o[2], o[3]);
  }
}

// ---------------------------------------------------------------------------
// Per-column stats of S0T [BATCH, SLOTS]: base max, sum(exp(x-max)), top-16
// (value desc, index asc on ties).  One block per column, 256 threads.
// ---------------------------------------------------------------------------
__global__ __launch_bounds__(256) void col_stats(
    const float* __restrict__ S0T, float* __restrict__ m_base,
    float* __restrict__ se_base, float* __restrict__ t16v, int* __restrict__ t16i)
{
  const int i = blockIdx.x;
  const int t = threadIdx.x;
  const float* col = S0T + (size_t)i * SLOTS;
  float v[16]; int ix[16];
  #pragma unroll
  for (int q = 0; q < 16; ++q) { v[q] = -1e30f; ix[q] = 0x7fffffff; }
  const int base = t * (SLOTS / 256);   // 128 contiguous per thread
  for (int u = 0; u < 128; u += 4) {
    float4 x4 = *(const float4*)(col + base + u);
    float xs[4] = {x4.x, x4.y, x4.z, x4.w};
    #pragma unroll
    for (int e = 0; e < 4; ++e) {
      float cv = xs[e]; int ci = base + u + e;
      if (cv > v[15] || (cv == v[15] && ci < ix[15])) {
        #pragma unroll
        for (int q = 0; q < 16; ++q) {
          bool better = (cv > v[q]) || (cv == v[q] && ci < ix[q]);
          if (better) { float tv = v[q]; v[q] = cv; cv = tv;
                        int   ti = ix[q]; ix[q] = ci; ci = ti; }
        }
      }
    }
  }
  __shared__ float lv[4096];
  __shared__ int   li[4096];
  __shared__ float wbv[4]; __shared__ int wbi[4], wbp[4];
  __shared__ float bcastV;
  #pragma unroll
  for (int q = 0; q < 16; ++q) { lv[t*16+q] = v[q]; li[t*16+q] = ix[q]; }
  for (int r = 0; r < 16; ++r) {
    __syncthreads();
    float bv2 = -1e30f; int bi2 = 0x7fffffff, bp2 = -1;
    for (int q = 0; q < 16; ++q) {
      int p = t*16 + q;
      float xv = lv[p]; int xi = li[p];
      if (xv > bv2 || (xv == bv2 && xi < bi2)) { bv2 = xv; bi2 = xi; bp2 = p; }
    }
    for (int off = 32; off; off >>= 1) {
      float ov = __shfl_xor(bv2, off);
      int   oi = __shfl_xor(bi2, off);
      int   op = __shfl_xor(bp2, off);
      if (ov > bv2 || (ov == bv2 && oi < bi2)) { bv2 = ov; bi2 = oi; bp2 = op; }
    }
    if ((t & 63) == 0) { wbv[t>>6] = bv2; wbi[t>>6] = bi2; wbp[t>>6] = bp2; }
    __syncthreads();
    if (t == 0) {
      float fv = wbv[0]; int fi = wbi[0], fp = wbp[0];
      for (int w2 = 1; w2 < 4; ++w2)
        if (wbv[w2] > fv || (wbv[w2] == fv && wbi[w2] < fi)) {
          fv = wbv[w2]; fi = wbi[w2]; fp = wbp[w2];
        }
      t16v[i*16 + r] = fv; t16i[i*16 + r] = fi;
      lv[fp] = -1e30f; li[fp] = 0x7fffffff;
      if (r == 0) bcastV = fv;
    }
  }
  __syncthreads();
  const float m = bcastV;
  float s = 0.f;
  for (int u = 0; u < 128; u += 4) {
    float4 x4 = *(const float4*)(col + base + u);
    s += __expf(x4.x - m) + __expf(x4.y - m) + __expf(x4.z - m) + __expf(x4.w - m);
  }
  for (int off = 32; off; off >>= 1) s += __shfl_xor(s, off);
  __shared__ float ws2[4];
  if ((t & 63) == 0) ws2[t>>6] = s;
  __syncthreads();
  if (t == 0) { se_base[i] = ws2[0]+ws2[1]+ws2[2]+ws2[3]; m_base[i] = m; }
}

// ---------------------------------------------------------------------------
// zero helper
// ---------------------------------------------------------------------------
__global__ void zero_kernel(float* __restrict__ p, int n)
{
  int idx = blockIdx.x * blockDim.x + threadIdx.x;
  if (idx < n) p[idx] = 0.0f;
}

// ---------------------------------------------------------------------------
// Sequential phase: single wave (64 threads). Per step i: corrected argmax,
// corrected softmax max m_i and denominator Z_i, correction coefficients
// Cadd[i,j] = exp(G[j,i]-m_i), Csub[i,j] = exp(S0T[i,slot_j]-m_i) for the
// latest-writer j's only.
// ---------------------------------------------------------------------------
__global__ __launch_bounds__(64) void seq_phase(
    const float* __restrict__ S0T, const float* __restrict__ G,
    const float* __restrict__ m_base, const float* __restrict__ se_base,
    const float* __restrict__ t16v, const int* __restrict__ t16i,
    int* __restrict__ slots, float* __restrict__ mOut, float* __restrict__ Zout,
    float* __restrict__ Cadd, float* __restrict__ Csub)
{
  const int lane = threadIdx.x;
  __shared__ unsigned int bitmap[SLOTS/32];    // written-slot bitmap, 4KB
  for (int q = lane; q < SLOTS/32; q += 64) bitmap[q] = 0u;
  bool alive[4] = {false,false,false,false};
  int  slotr[4] = {0,0,0,0};
  __syncthreads();
  for (int i = 0; i < BATCH; ++i) {
    float g[4], sv[4];
    #pragma unroll
    for (int r = 0; r < 4; ++r) {
      g[r] = -1e30f; sv[r] = -1e30f;
      if (alive[r]) {
        g[r]  = G[(size_t)i*BATCH + lane + 64*r];
        sv[r] = S0T[(size_t)i*SLOTS + slotr[r]];
      }
    }
    // best override candidate (value, slot)
    float bv = -1e30f; int bs = 0x7fffffff;
    #pragma unroll
    for (int r = 0; r < 4; ++r)
      if (alive[r] && (g[r] > bv || (g[r] == bv && slotr[r] < bs))) { bv = g[r]; bs = slotr[r]; }
    for (int off = 32; off; off >>= 1) {
      float ov = __shfl_xor(bv, off); int os = __shfl_xor(bs, off);
      if (ov > bv || (ov == bv && os < bs)) { bv = ov; bs = os; }
    }
    const float mb = m_base[i];
    const float mi = fmaxf(mb, bv);
    float z = 0.f;
    float ca[4], cs[4];
    #pragma unroll
    for (int r = 0; r < 4; ++r) {
      ca[r] = 0.f; cs[r] = 0.f;
      if (alive[r]) {
        ca[r] = __expf(g[r]  - mi);
        cs[r] = __expf(sv[r] - mi);
        z += ca[r] - cs[r];
      }
    }
    for (int off = 32; off; off >>= 1) z += __shfl_xor(z, off);
    const float Z = se_base[i] * __expf(mb - mi) + z;
    #pragma unroll
    for (int r = 0; r < 4; ++r) {
      if (alive[r]) {
        Cadd[(size_t)i*BATCH + lane + 64*r] = ca[r];
        Csub[(size_t)i*BATCH + lane + 64*r] = cs[r];
      }
    }
    // best base candidate among top16 entries not yet written
    float bbv = -1e30f; int bbi = 0x7fffffff;
    if (lane < 16) {
      float v0 = t16v[i*16 + lane]; int i0 = t16i[i*16 + lane];
      bool wr = (bitmap[i0 >> 5] >> (i0 & 31)) & 1u;
      if (!wr) { bbv = v0; bbi = i0; }
    }
    for (int off = 32; off; off >>= 1) {
      float ov = __shfl_xor(bbv, off); int oi = __shfl_xor(bbi, off);
      if (ov > bbv || (ov == bbv && oi < bbi)) { bbv = ov; bbi = oi; }
    }
    if (bbv == -1e30f) {           // all top-16 overridden (≈never): full scan
      float fv = -1e30f; int fi = 0x7fffffff;
      for (int s = lane; s < SLOTS; s += 64) {
        bool wr = (bitmap[s >> 5] >> (s & 31)) & 1u;
        if (!wr) {
          float x = S0T[(size_t)i*SLOTS + s];
          if (x > fv) { fv = x; fi = s; }
        }
      }
      for (int off = 32; off; off >>= 1) {
        float ov = __shfl_xor(fv, off); int oi = __shfl_xor(fi, off);
        if (ov > fv || (ov == fv && oi < fi)) { fv = ov; fi = oi; }
      }
      bbv = fv; bbi = fi;
    }
    int sloti;
    if (bbv > bv || (bbv == bv && bbi < bs)) sloti = bbi; else sloti = bs;
    #pragma unroll
    for (int r = 0; r < 4; ++r)
      if (alive[r] && slotr[r] == sloti) alive[r] = false;
    const int r_new = i >> 6;
    #pragma unroll
    for (int r = 0; r < 4; ++r)
      if (r == r_new && lane == (i & 63)) { alive[r] = true; slotr[r] = sloti; }
    if (lane == 0) {
      bitmap[sloti >> 5] |= (1u << (sloti & 31));
      slots[i] = sloti; mOut[i] = mi; Zout[i] = Z;
    }
    __syncthreads();
  }
}

// ---------------------------------------------------------------------------
// exp-GEMM: part tiles of read_num[i,d] = sum_s exp(S0T[i,s]-m_i)*V[s,d]
// Mt=256 (full), Nt=64, split-K=32.  grid (8 n-tiles, 32 k-chunks), 256 thr.
// Deterministic: partials written per block, reduced by ksum.
// ---------------------------------------------------------------------------
__global__ __launch_bounds__(256) void exp_gemm(
    const float* __restrict__ S0T, const float* __restrict__ V,
    const float* __restrict__ mArr, float* __restrict__ part)
{
  __shared__ __align__(16) float Es[16][260];
  __shared__ __align__(16) float Vs[16][68];
  const int n0  = blockIdx.x * 64;
  const int k0b = blockIdx.y * (SLOTS/32);    // 1024-slot chunk
  const int t = threadIdx.x;
  const int tx = t & 15, ty = t >> 4;
  const float mrow = mArr[t];                  // thread t loads score row t
  const int vrow = t >> 4;
  const int vcol = (t & 15) * 4;
  float acc[16][4] = {};
  for (int kc = 0; kc < SLOTS/32; kc += 16) {
    const int k0 = k0b + kc;
    const float* srce = S0T + (size_t)t * SLOTS + k0;
    float4 x0 = *(const float4*)(srce + 0);
    float4 x1 = *(const float4*)(srce + 4);
    float4 x2 = *(const float4*)(srce + 8);
    float4 x3 = *(const float4*)(srce + 12);
    float4 vv = *(const float4*)(V + (size_t)(k0 + vrow) * DIM + n0 + vcol);
    __syncthreads();
    Es[ 0][t] = __expf(x0.x - mrow); Es[ 1][t] = __expf(x0.y - mrow);
    Es[ 2][t] = __expf(x0.z - mrow); Es[ 3][t] = __expf(x0.w - mrow);
    Es[ 4][t] = __expf(x1.x - mrow); Es[ 5][t] = __expf(x1.y - mrow);
    Es[ 6][t] = __expf(x1.z - mrow); Es[ 7][t] = __expf(x1.w - mrow);
    Es[ 8][t] = __expf(x2.x - mrow); Es[ 9][t] = __expf(x2.y - mrow);
    Es[10][t] = __expf(x2.z - mrow); Es[11][t] = __expf(x2.w - mrow);
    Es[12][t] = __expf(x3.x - mrow); Es[13][t] = __expf(x3.y - mrow);
    Es[14][t] = __expf(x3.z - mrow); Es[15][t] = __expf(x3.w - mrow);
    *(float4*)&Vs[vrow][vcol] = vv;
    __syncthreads();
    #pragma unroll
    for (int k = 0; k < 16; ++k) {
      const float4 b4 = *(const float4*)&Vs[k][tx*4];
      const float bb[4] = {b4.x, b4.y, b4.z, b4.w};
      #pragma unroll
      for (int uq = 0; uq < 4; ++uq) {
        const float4 a4 = *(const float4*)&Es[k][ty*16 + uq*4];
        const float aa[4] = {a4.x, a4.y, a4.z, a4.w};
        #pragma unroll
        for (int e = 0; e < 4; ++e)
          #pragma unroll
          for (int v2 = 0; v2 < 4; ++v2)
            acc[uq*4+e][v2] = fmaf(aa[e], bb[v2], acc[uq*4+e][v2]);
      }
    }
  }
  const size_t pbase = ((size_t)(blockIdx.y * 8 + blockIdx.x)) * 16384;
  #pragma unroll
  for (int u = 0; u < 16; ++u) {
    *(float4*)(part + pbase + (size_t)(ty*16 + u)*64 + tx*4) =
        make_float4(acc[u][0], acc[u][1], acc[u][2], acc[u][3]);
  }
}

// reduce split-K partials: out[m,n] = sum_kb part[(kb*8+nt)*16384 + m*64 + c]
__global__ __launch_bounds__(256) void ksum(
    const float* __restrict__ part, float* __restrict__ out)
{
  int idx = blockIdx.x * 256 + threadIdx.x;  // 131072 total
  int m = idx >> 9; int n = idx & 511;
  int nt = n >> 6; int c = n & 63;
  float s = 0.f;
  for (int kb = 0; kb < 32; ++kb)
    s += part[((size_t)(kb*8 + nt)) * 16384 + m*64 + c];
  out[idx] = s;
}

// ---------------------------------------------------------------------------
// read_val = (read_num + Cadd@WV - Csub@mem_vals[slots]) / Z ; build merged.
// One block per step i; thread t covers cols t and t+256.
// ---------------------------------------------------------------------------
__global__ __launch_bounds__(256) void readval_merge(
    const float* __restrict__ read_num, const float* __restrict__ Cadd,
    const float* __restrict__ Csub, const float* __restrict__ WVp,
    const float* __restrict__ mem_vals, const int* __restrict__ slots,
    const float* __restrict__ Zarr, const float* __restrict__ S_t,
    float* __restrict__ merged)
{
  const int i = blockIdx.x;
  const int t = threadIdx.x;
  merged[(size_t)i*1024 + t]        = S_t[(size_t)i*DIM + t];
  merged[(size_t)i*1024 + 256 + t]  = S_t[(size_t)i*DIM + 256 + t];
  float acc0 = read_num[(size_t)i*DIM + t];
  float acc1 = read_num[(size_t)i*DIM + 256 + t];
  for (int j = 0; j < BATCH; ++j) {
    float caj = Cadd[(size_t)i*BATCH + j];
    float csj = Csub[(size_t)i*BATCH + j];
    if (caj != 0.f || csj != 0.f) {
      int sj = slots[j];
      acc0 += caj * WVp[(size_t)j*DIM + t]       - csj * mem_vals[(size_t)sj*DIM + t];
      acc1 += caj * WVp[(size_t)j*DIM + 256 + t] - csj * mem_vals[(size_t)sj*DIM + 256 + t];
    }
  }
  const float invZ = 1.0f / Zarr[i];
  merged[(size_t)i*1024 + 512 + t] = acc0 * invZ;
  merged[(size_t)i*1024 + 768 + t] = acc1 * invZ;
}

// ---------------------------------------------------------------------------
extern "C" void kernel_launch(void* const* d_in, const int* in_sizes, int n_in,
                              void* d_out, int out_size, void* d_ws, size_t ws_size,
                              hipStream_t stream)
{
  (void)in_sizes; (void)n_in; (void)out_size; (void)ws_size;
  const float* S_t      = (const float*)d_in[0];
  const float* mem_keys = (const float*)d_in[1];
  const float* mem_vals = (const float*)d_in[2];
  const float* Wk       = (const float*)d_in[3];
  const float* bk       = (const float*)d_in[4];
  const float* Wv       = (const float*)d_in[5];
  const float* bv       = (const float*)d_in[6];
  const float* W1       = (const float*)d_in[7];
  const float* b1       = (const float*)d_in[8];
  const float* W2       = (const float*)d_in[9];
  const float* b2       = (const float*)d_in[10];
  float* out = (float*)d_out;

  float* ws = (float*)d_ws;
  float* Kp       = ws + 0;         // [256,512]
  float* WVp      = ws + 131072;    // [256,512]
  float* G        = ws + 262144;    // [256,256]
  float* S0T      = ws + 327680;    // [256,32768]
  float* m_base   = ws + 8716288;   // [256]
  float* se_base  = ws + 8716544;   // [256]
  float* t16v     = ws + 8716800;   // [256,16]
  int*   t16i     = (int*)(ws + 8720896);
  int*   slots    = (int*)(ws + 8724992);
  float* mOut     = ws + 8725248;
  float* Zout     = ws + 8725504;
  float* Cadd     = ws + 8725760;   // [256,256]
  float* Csub     = ws + 8791296;   // [256,256]
  float* read_num = ws + 8856832;   // [256,512]
  float* merged   = ws + 8987904;   // [256,1024]
  float* hid      = ws + 9250048;   // [256,2048]
  float* part     = ws + 9774336;   // [256 blocks][256,64]

  // phase 1: projections + gram + base scores
  gemm_bt<<<dim3(4, 8),   dim3(256), 0, stream>>>(S_t, Wk, bk, Kp,  256, 512,   512, 0);
  gemm_bt<<<dim3(4, 8),   dim3(256), 0, stream>>>(S_t, Wv, bv, WVp, 256, 512,   512, 0);
  gemm_bt<<<dim3(4, 4),   dim3(256), 0, stream>>>(Kp,  Kp, nullptr, G, 256, 256, 512, 0);
  gemm_bt<<<dim3(4, 512), dim3(256), 0, stream>>>(Kp, mem_keys, nullptr, S0T, 256, 32768, 512, 0);

  // phase 2: per-column stats, then tiny sequential recurrence
  col_stats<<<dim3(256), dim3(256), 0, stream>>>(S0T, m_base, se_base, t16v, t16i);
  zero_kernel<<<dim3(512), dim3(256), 0, stream>>>(Cadd, 131072);  // Cadd+Csub contiguous
  seq_phase<<<dim3(1), dim3(64), 0, stream>>>(S0T, G, m_base, se_base, t16v, t16i,
                                              slots, mOut, Zout, Cadd, Csub);

  // phase 3: batched read + corrections
  exp_gemm<<<dim3(8, 32), dim3(256), 0, stream>>>(S0T, mem_vals, mOut, part);
  ksum<<<dim3(512), dim3(256), 0, stream>>>(part, read_num);
  readval_merge<<<dim3(256), dim3(256), 0, stream>>>(read_num, Cadd, Csub, WVp,
                                                     mem_vals, slots, Zout, S_t, merged);

  // phase 4: MLP
  gemm_bt<<<dim3(4, 32), dim3(256), 0, stream>>>(merged, W1, b1, hid, 256, 2048, 1024, 1);
  gemm_bt<<<dim3(4, 8),  dim3(256), 0, stream>>>(hid,    W2, b2, out, 256, 512,  2048, 0);
}

// Round 2
// 1310.457 us; speedup vs baseline: 1.2356x; 1.2356x over previous
//
#include <hip/hip_runtime.h>
#include <cstdint>
#include <cstddef>

#define BATCH 256
#define DIM   512
#define HIDN  2048
#define SLOTS 32768

// ---------------------------------------------------------------------------
// Generic tiled fp32 GEMM: C[M,N] = act(A @ B^T + bias), A[M,K], B[N,K]
// M%64==0, N%64==0, K%16==0. Tile 64x64, TK=16, 256 threads, 4x4 acc/thread.
// ---------------------------------------------------------------------------
__global__ __launch_bounds__(256) void gemm_bt(
    const float* __restrict__ A, const float* __restrict__ B,
    const float* __restrict__ bias, float* __restrict__ C,
    int M, int N, int K, int relu)
{
  __shared__ __align__(16) float As[16][68];
  __shared__ __align__(16) float Bs[16][68];
  const int m0 = blockIdx.x * 64;
  const int n0 = blockIdx.y * 64;
  const int t  = threadIdx.x;
  const int tx = t & 15, ty = t >> 4;
  const int lr = t >> 2;          // 0..63
  const int lc = (t & 3) * 4;     // 0,4,8,12
  float acc[4][4] = {};
  for (int k0 = 0; k0 < K; k0 += 16) {
    float4 a = *(const float4*)(A + (size_t)(m0 + lr) * K + k0 + lc);
    float4 b = *(const float4*)(B + (size_t)(n0 + lr) * K + k0 + lc);
    __syncthreads();
    As[lc+0][lr] = a.x; As[lc+1][lr] = a.y; As[lc+2][lr] = a.z; As[lc+3][lr] = a.w;
    Bs[lc+0][lr] = b.x; Bs[lc+1][lr] = b.y; Bs[lc+2][lr] = b.z; Bs[lc+3][lr] = b.w;
    __syncthreads();
    #pragma unroll
    for (int k = 0; k < 16; ++k) {
      const float4 a4 = *(const float4*)&As[k][ty*4];
      const float4 b4 = *(const float4*)&Bs[k][tx*4];
      const float aa[4] = {a4.x, a4.y, a4.z, a4.w};
      const float bb[4] = {b4.x, b4.y, b4.z, b4.w};
      #pragma unroll
      for (int u = 0; u < 4; ++u)
        #pragma unroll
        for (int v = 0; v < 4; ++v)
          acc[u][v] = fmaf(aa[u], bb[v], acc[u][v]);
    }
  }
  #pragma unroll
  for (int u = 0; u < 4; ++u) {
    const int m = m0 + ty*4 + u;
    float o[4];
    #pragma unroll
    for (int v = 0; v < 4; ++v) {
      float c = acc[u][v];
      if (bias) c += bias[n0 + tx*4 + v];
      if (relu) c = fmaxf(c, 0.0f);
      o[v] = c;
    }
    *(float4*)(C + (size_t)m * N + n0 + tx*4) = make_float4(o[0], o[1], o[2], o[3]);
  }
}

// ---------------------------------------------------------------------------
// Per-column stats of S0T [BATCH, SLOTS]: base max, sum(exp(x-max)), top-16
// (value desc, index asc on ties).  One block per column, 256 threads.
// ---------------------------------------------------------------------------
__global__ __launch_bounds__(256) void col_stats(
    const float* __restrict__ S0T, float* __restrict__ m_base,
    float* __restrict__ se_base, float* __restrict__ t16v, int* __restrict__ t16i)
{
  const int i = blockIdx.x;
  const int t = threadIdx.x;
  const float* col = S0T + (size_t)i * SLOTS;
  float v[16]; int ix[16];
  #pragma unroll
  for (int q = 0; q < 16; ++q) { v[q] = -1e30f; ix[q] = 0x7fffffff; }
  const int base = t * (SLOTS / 256);   // 128 contiguous per thread
  for (int u = 0; u < 128; u += 4) {
    float4 x4 = *(const float4*)(col + base + u);
    float xs[4] = {x4.x, x4.y, x4.z, x4.w};
    #pragma unroll
    for (int e = 0; e < 4; ++e) {
      float cv = xs[e]; int ci = base + u + e;
      if (cv > v[15] || (cv == v[15] && ci < ix[15])) {
        #pragma unroll
        for (int q = 0; q < 16; ++q) {
          bool better = (cv > v[q]) || (cv == v[q] && ci < ix[q]);
          if (better) { float tv = v[q]; v[q] = cv; cv = tv;
                        int   ti = ix[q]; ix[q] = ci; ci = ti; }
        }
      }
    }
  }
  __shared__ float lv[4096];
  __shared__ int   li[4096];
  __shared__ float wbv[4]; __shared__ int wbi[4], wbp[4];
  __shared__ float bcastV;
  #pragma unroll
  for (int q = 0; q < 16; ++q) { lv[t*16+q] = v[q]; li[t*16+q] = ix[q]; }
  for (int r = 0; r < 16; ++r) {
    __syncthreads();
    float bv2 = -1e30f; int bi2 = 0x7fffffff, bp2 = -1;
    for (int q = 0; q < 16; ++q) {
      int p = t*16 + q;
      float xv = lv[p]; int xi = li[p];
      if (xv > bv2 || (xv == bv2 && xi < bi2)) { bv2 = xv; bi2 = xi; bp2 = p; }
    }
    for (int off = 32; off; off >>= 1) {
      float ov = __shfl_xor(bv2, off);
      int   oi = __shfl_xor(bi2, off);
      int   op = __shfl_xor(bp2, off);
      if (ov > bv2 || (ov == bv2 && oi < bi2)) { bv2 = ov; bi2 = oi; bp2 = op; }
    }
    if ((t & 63) == 0) { wbv[t>>6] = bv2; wbi[t>>6] = bi2; wbp[t>>6] = bp2; }
    __syncthreads();
    if (t == 0) {
      float fv = wbv[0]; int fi = wbi[0], fp = wbp[0];
      for (int w2 = 1; w2 < 4; ++w2)
        if (wbv[w2] > fv || (wbv[w2] == fv && wbi[w2] < fi)) {
          fv = wbv[w2]; fi = wbi[w2]; fp = wbp[w2];
        }
      t16v[i*16 + r] = fv; t16i[i*16 + r] = fi;
      lv[fp] = -1e30f; li[fp] = 0x7fffffff;
      if (r == 0) bcastV = fv;
    }
  }
  __syncthreads();
  const float m = bcastV;
  float s = 0.f;
  for (int u = 0; u < 128; u += 4) {
    float4 x4 = *(const float4*)(col + base + u);
    s += __expf(x4.x - m) + __expf(x4.y - m) + __expf(x4.z - m) + __expf(x4.w - m);
  }
  for (int off = 32; off; off >>= 1) s += __shfl_xor(s, off);
  __shared__ float ws2[4];
  if ((t & 63) == 0) ws2[t>>6] = s;
  __syncthreads();
  if (t == 0) { se_base[i] = ws2[0]+ws2[1]+ws2[2]+ws2[3]; m_base[i] = m; }
}

// ---------------------------------------------------------------------------
// Slim sequential phase: single wave, ONLY the argmax/slot recurrence.
// Per step: merged (value, slot-index) max over {alive writers' G[i,j]} ∪
// {unwritten top-16 of row i}. G rows register-prefetched distance 4 (no
// __syncthreads in loop so vmcnt never drains); bitmap + t16 LDS-resident.
// mi/Z/Cadd/Csub are deferred to coef_kernel (fully parallel).
// ---------------------------------------------------------------------------
__global__ __launch_bounds__(64) void seq_slim(
    const float* __restrict__ S0T, const float* __restrict__ G,
    const float* __restrict__ t16v, const int* __restrict__ t16i,
    int* __restrict__ slots)
{
  const int lane = threadIdx.x;
  __shared__ unsigned int bitmap[SLOTS/32];   // 4 KB
  __shared__ float sv16[BATCH*16];            // 16 KB
  __shared__ int   si16[BATCH*16];            // 16 KB
  volatile unsigned int* vbm = bitmap;
  for (int q = lane; q < SLOTS/32; q += 64) bitmap[q] = 0u;
  for (int q = lane; q < BATCH*16; q += 64) { sv16[q] = t16v[q]; si16[q] = t16i[q]; }
  __syncthreads();

  bool alive[4] = {false,false,false,false};
  int  slotr[4] = {0,0,0,0};
  float gbuf[4][4];                            // rolling rows i..i+3
  #pragma unroll
  for (int u = 0; u < 4; ++u)
    #pragma unroll
    for (int r = 0; r < 4; ++r)
      gbuf[u][r] = G[(size_t)u*BATCH + lane + 64*r];

  auto step = [&](int i, float (&g)[4]) {
    float bv = -1e30f; int bs = 0x7fffffff;
    #pragma unroll
    for (int r = 0; r < 4; ++r)
      if (alive[r]) {
        if (g[r] > bv || (g[r] == bv && slotr[r] < bs)) { bv = g[r]; bs = slotr[r]; }
      }
    bool anyBase = false;
    if (lane < 16) {
      float v0 = sv16[i*16 + lane]; int i0 = si16[i*16 + lane];
      bool wr = (vbm[i0 >> 5] >> (i0 & 31)) & 1u;
      if (!wr) {
        anyBase = true;
        if (v0 > bv || (v0 == bv && i0 < bs)) { bv = v0; bs = i0; }
      }
    }
    if (__ballot(anyBase ? 1 : 0) == 0ULL) {
      // cold fallback (all top-16 already written): full row scan
      float fv = -1e30f; int fi = 0x7fffffff;
      for (int s = lane; s < SLOTS; s += 64) {
        bool wr = (vbm[s >> 5] >> (s & 31)) & 1u;
        if (!wr) {
          float x = S0T[(size_t)i*SLOTS + s];
          if (x > fv || (x == fv && s < fi)) { fv = x; fi = s; }
        }
      }
      if (fv > bv || (fv == bv && fi < bs)) { bv = fv; bs = fi; }
    }
    #pragma unroll
    for (int off = 32; off; off >>= 1) {
      float ov = __shfl_xor(bv, off); int os = __shfl_xor(bs, off);
      if (ov > bv || (ov == bv && os < bs)) { bv = ov; bs = os; }
    }
    const int sloti = bs;
    #pragma unroll
    for (int r = 0; r < 4; ++r)
      if (alive[r] && slotr[r] == sloti) alive[r] = false;
    #pragma unroll
    for (int r = 0; r < 4; ++r)
      if ((i >> 6) == r && lane == (i & 63)) { alive[r] = true; slotr[r] = sloti; }
    if (lane == 0) {
      slots[i] = sloti;
      vbm[sloti >> 5] = vbm[sloti >> 5] | (1u << (sloti & 31));
    }
    __builtin_amdgcn_wave_barrier();   // compiler fence; DS pipe is per-wave in-order
  };

  for (int ib = 0; ib < BATCH; ib += 4) {
    #pragma unroll
    for (int u = 0; u < 4; ++u) {
      step(ib + u, gbuf[u]);
      const int ip = (ib + u + 4 < BATCH) ? (ib + u + 4) : (BATCH - 1);
      #pragma unroll
      for (int r = 0; r < 4; ++r)
        gbuf[u][r] = G[(size_t)ip*BATCH + lane + 64*r];
    }
  }
}

// ---------------------------------------------------------------------------
// nxt[j] = first step k>j that rewrites slots[j] (else INT_MAX).
// ---------------------------------------------------------------------------
__global__ __launch_bounds__(256) void nxt_kernel(
    const int* __restrict__ slots, int* __restrict__ nxt)
{
  __shared__ int sh[BATCH];
  const int j = threadIdx.x;
  sh[j] = slots[j];
  __syncthreads();
  const int sj = sh[j];
  int n = 0x7fffffff;
  for (int k = j + 1; k < BATCH; ++k)
    if (sh[k] == sj) { n = k; break; }
  nxt[j] = n;
}

// ---------------------------------------------------------------------------
// Parallel reconstruction of mi, Z, Cadd, Csub from slots/nxt.
// Block i, thread j: alive = j latest writer of slots[j] before step i.
// ---------------------------------------------------------------------------
__global__ __launch_bounds__(256) void coef_kernel(
    const float* __restrict__ S0T, const float* __restrict__ G,
    const int* __restrict__ slots, const int* __restrict__ nxt,
    const float* __restrict__ m_base, const float* __restrict__ se_base,
    float* __restrict__ mOut, float* __restrict__ Zout,
    float* __restrict__ Cadd, float* __restrict__ Csub)
{
  const int i = blockIdx.x, j = threadIdx.x;
  const bool alive = (j < i) && (nxt[j] >= i);
  const float g = alive ? G[(size_t)i*BATCH + j] : -1e30f;
  float bv = g;
  #pragma unroll
  for (int off = 32; off; off >>= 1) bv = fmaxf(bv, __shfl_xor(bv, off));
  __shared__ float red[4];
  if ((j & 63) == 0) red[j >> 6] = bv;
  __syncthreads();
  const float mb = m_base[i];
  const float mi = fmaxf(fmaxf(fmaxf(red[0], red[1]), fmaxf(red[2], red[3])), mb);
  const float sv = alive ? S0T[(size_t)i*SLOTS + slots[j]] : 0.f;
  const float ca = alive ? __expf(g - mi) : 0.f;
  const float cs = alive ? __expf(sv - mi) : 0.f;
  Cadd[(size_t)i*BATCH + j] = ca;
  Csub[(size_t)i*BATCH + j] = cs;
  float z = ca - cs;
  #pragma unroll
  for (int off = 32; off; off >>= 1) z += __shfl_xor(z, off);
  __syncthreads();
  if ((j & 63) == 0) red[j >> 6] = z;
  __syncthreads();
  if (j == 0) {
    mOut[i] = mi;
    Zout[i] = se_base[i] * __expf(mb - mi) + red[0] + red[1] + red[2] + red[3];
  }
}

// ---------------------------------------------------------------------------
// exp-GEMM: part tiles of read_num[i,d] = sum_s exp(S0T[i,s]-m_i)*V[s,d]
// Mt=256 (full), Nt=64, split-K=32.  grid (8 n-tiles, 32 k-chunks), 256 thr.
// ---------------------------------------------------------------------------
__global__ __launch_bounds__(256) void exp_gemm(
    const float* __restrict__ S0T, const float* __restrict__ V,
    const float* __restrict__ mArr, float* __restrict__ part)
{
  __shared__ __align__(16) float Es[16][260];
  __shared__ __align__(16) float Vs[16][68];
  const int n0  = blockIdx.x * 64;
  const int k0b = blockIdx.y * (SLOTS/32);    // 1024-slot chunk
  const int t = threadIdx.x;
  const int tx = t & 15, ty = t >> 4;
  const float mrow = mArr[t];                  // thread t loads score row t
  const int vrow = t >> 4;
  const int vcol = (t & 15) * 4;
  float acc[16][4] = {};
  for (int kc = 0; kc < SLOTS/32; kc += 16) {
    const int k0 = k0b + kc;
    const float* srce = S0T + (size_t)t * SLOTS + k0;
    float4 x0 = *(const float4*)(srce + 0);
    float4 x1 = *(const float4*)(srce + 4);
    float4 x2 = *(const float4*)(srce + 8);
    float4 x3 = *(const float4*)(srce + 12);
    float4 vv = *(const float4*)(V + (size_t)(k0 + vrow) * DIM + n0 + vcol);
    __syncthreads();
    Es[ 0][t] = __expf(x0.x - mrow); Es[ 1][t] = __expf(x0.y - mrow);
    Es[ 2][t] = __expf(x0.z - mrow); Es[ 3][t] = __expf(x0.w - mrow);
    Es[ 4][t] = __expf(x1.x - mrow); Es[ 5][t] = __expf(x1.y - mrow);
    Es[ 6][t] = __expf(x1.z - mrow); Es[ 7][t] = __expf(x1.w - mrow);
    Es[ 8][t] = __expf(x2.x - mrow); Es[ 9][t] = __expf(x2.y - mrow);
    Es[10][t] = __expf(x2.z - mrow); Es[11][t] = __expf(x2.w - mrow);
    Es[12][t] = __expf(x3.x - mrow); Es[13][t] = __expf(x3.y - mrow);
    Es[14][t] = __expf(x3.z - mrow); Es[15][t] = __expf(x3.w - mrow);
    *(float4*)&Vs[vrow][vcol] = vv;
    __syncthreads();
    #pragma unroll
    for (int k = 0; k < 16; ++k) {
      const float4 b4 = *(const float4*)&Vs[k][tx*4];
      const float bb[4] = {b4.x, b4.y, b4.z, b4.w};
      #pragma unroll
      for (int uq = 0; uq < 4; ++uq) {
        const float4 a4 = *(const float4*)&Es[k][ty*16 + uq*4];
        const float aa[4] = {a4.x, a4.y, a4.z, a4.w};
        #pragma unroll
        for (int e = 0; e < 4; ++e)
          #pragma unroll
          for (int v2 = 0; v2 < 4; ++v2)
            acc[uq*4+e][v2] = fmaf(aa[e], bb[v2], acc[uq*4+e][v2]);
      }
    }
  }
  const size_t pbase = ((size_t)(blockIdx.y * 8 + blockIdx.x)) * 16384;
  #pragma unroll
  for (int u = 0; u < 16; ++u) {
    *(float4*)(part + pbase + (size_t)(ty*16 + u)*64 + tx*4) =
        make_float4(acc[u][0], acc[u][1], acc[u][2], acc[u][3]);
  }
}

// reduce split-K partials: out[m,n] = sum_kb part[(kb*8+nt)*16384 + m*64 + c]
__global__ __launch_bounds__(256) void ksum(
    const float* __restrict__ part, float* __restrict__ out)
{
  int idx = blockIdx.x * 256 + threadIdx.x;  // 131072 total
  int m = idx >> 9; int n = idx & 511;
  int nt = n >> 6; int c = n & 63;
  float s = 0.f;
  for (int kb = 0; kb < 32; ++kb)
    s += part[((size_t)(kb*8 + nt)) * 16384 + m*64 + c];
  out[idx] = s;
}

// ---------------------------------------------------------------------------
// read_val = (read_num + Cadd@WV - Csub@mem_vals[slots]) / Z ; build merged.
// ---------------------------------------------------------------------------
__global__ __launch_bounds__(256) void readval_merge(
    const float* __restrict__ read_num, const float* __restrict__ Cadd,
    const float* __restrict__ Csub, const float* __restrict__ WVp,
    const float* __restrict__ mem_vals, const int* __restrict__ slots,
    const float* __restrict__ Zarr, const float* __restrict__ S_t,
    float* __restrict__ merged)
{
  const int i = blockIdx.x;
  const int t = threadIdx.x;
  merged[(size_t)i*1024 + t]        = S_t[(size_t)i*DIM + t];
  merged[(size_t)i*1024 + 256 + t]  = S_t[(size_t)i*DIM + 256 + t];
  float acc0 = read_num[(size_t)i*DIM + t];
  float acc1 = read_num[(size_t)i*DIM + 256 + t];
  for (int j = 0; j < BATCH; ++j) {
    float caj = Cadd[(size_t)i*BATCH + j];
    float csj = Csub[(size_t)i*BATCH + j];
    if (caj != 0.f || csj != 0.f) {
      int sj = slots[j];
      acc0 += caj * WVp[(size_t)j*DIM + t]       - csj * mem_vals[(size_t)sj*DIM + t];
      acc1 += caj * WVp[(size_t)j*DIM + 256 + t] - csj * mem_vals[(size_t)sj*DIM + 256 + t];
    }
  }
  const float invZ = 1.0f / Zarr[i];
  merged[(size_t)i*1024 + 512 + t] = acc0 * invZ;
  merged[(size_t)i*1024 + 768 + t] = acc1 * invZ;
}

// ---------------------------------------------------------------------------
extern "C" void kernel_launch(void* const* d_in, const int* in_sizes, int n_in,
                              void* d_out, int out_size, void* d_ws, size_t ws_size,
                              hipStream_t stream)
{
  (void)in_sizes; (void)n_in; (void)out_size; (void)ws_size;
  const float* S_t      = (const float*)d_in[0];
  const float* mem_keys = (const float*)d_in[1];
  const float* mem_vals = (const float*)d_in[2];
  const float* Wk       = (const float*)d_in[3];
  const float* bk       = (const float*)d_in[4];
  const float* Wv       = (const float*)d_in[5];
  const float* bv       = (const float*)d_in[6];
  const float* W1       = (const float*)d_in[7];
  const float* b1       = (const float*)d_in[8];
  const float* W2       = (const float*)d_in[9];
  const float* b2       = (const float*)d_in[10];
  float* out = (float*)d_out;

  float* ws = (float*)d_ws;
  float* Kp       = ws + 0;         // [256,512]
  float* WVp      = ws + 131072;    // [256,512]
  float* G        = ws + 262144;    // [256,256]
  float* S0T      = ws + 327680;    // [256,32768]
  float* m_base   = ws + 8716288;   // [256]
  float* se_base  = ws + 8716544;   // [256]
  float* t16v     = ws + 8716800;   // [256,16]
  int*   t16i     = (int*)(ws + 8720896);
  int*   slots    = (int*)(ws + 8724992);
  int*   nxt      = (int*)(ws + 8725248);
  float* mOut     = ws + 8725504;
  float* Zout     = ws + 8725760;
  float* Cadd     = ws + 8726016;   // [256,256]
  float* Csub     = ws + 8791552;   // [256,256]
  float* read_num = ws + 8857088;   // [256,512]
  float* merged   = ws + 8988160;   // [256,1024]
  float* hid      = ws + 9250304;   // [256,2048]
  float* part     = ws + 9774592;   // [256 blocks][256,64]

  // phase 1: projections + gram + base scores
  gemm_bt<<<dim3(4, 8),   dim3(256), 0, stream>>>(S_t, Wk, bk, Kp,  256, 512,   512, 0);
  gemm_bt<<<dim3(4, 8),   dim3(256), 0, stream>>>(S_t, Wv, bv, WVp, 256, 512,   512, 0);
  gemm_bt<<<dim3(4, 4),   dim3(256), 0, stream>>>(Kp,  Kp, nullptr, G, 256, 256, 512, 0);
  gemm_bt<<<dim3(4, 512), dim3(256), 0, stream>>>(Kp, mem_keys, nullptr, S0T, 256, 32768, 512, 0);

  // phase 2: per-column stats, slim sequential recurrence, parallel coefs
  col_stats<<<dim3(256), dim3(256), 0, stream>>>(S0T, m_base, se_base, t16v, t16i);
  seq_slim<<<dim3(1), dim3(64), 0, stream>>>(S0T, G, t16v, t16i, slots);
  nxt_kernel<<<dim3(1), dim3(256), 0, stream>>>(slots, nxt);
  coef_kernel<<<dim3(256), dim3(256), 0, stream>>>(S0T, G, slots, nxt, m_base, se_base,
                                                   mOut, Zout, Cadd, Csub);

  // phase 3: batched read + corrections
  exp_gemm<<<dim3(8, 32), dim3(256), 0, stream>>>(S0T, mem_vals, mOut, part);
  ksum<<<dim3(512), dim3(256), 0, stream>>>(part, read_num);
  readval_merge<<<dim3(256), dim3(256), 0, stream>>>(read_num, Cadd, Csub, WVp,
                                                     mem_vals, slots, Zout, S_t, merged);

  // phase 4: MLP
  gemm_bt<<<dim3(4, 32), dim3(256), 0, stream>>>(merged, W1, b1, hid, 256, 2048, 1024, 1);
  gemm_bt<<<dim3(4, 8),  dim3(256), 0, stream>>>(hid,    W2, b2, out, 256, 512,  2048, 0);
}

// Round 3
// 1150.881 us; speedup vs baseline: 1.4070x; 1.1387x over previous
//
#include <hip/hip_runtime.h>
#include <cstdint>
#include <cstddef>

#define BATCH 256
#define DIM   512
#define HIDN  2048
#define SLOTS 32768

// ---------------------------------------------------------------------------
// Small tiled fp32 GEMM (kept for low-N shapes): C = act(A @ B^T + bias)
// Tile 64x64, TK=16, 256 threads, 4x4 acc/thread.
// ---------------------------------------------------------------------------
__global__ __launch_bounds__(256) void gemm_bt(
    const float* __restrict__ A, const float* __restrict__ B,
    const float* __restrict__ bias, float* __restrict__ C,
    int M, int N, int K, int relu)
{
  __shared__ __align__(16) float As[16][68];
  __shared__ __align__(16) float Bs[16][68];
  const int m0 = blockIdx.x * 64;
  const int n0 = blockIdx.y * 64;
  const int t  = threadIdx.x;
  const int tx = t & 15, ty = t >> 4;
  const int lr = t >> 2;
  const int lc = (t & 3) * 4;
  float acc[4][4] = {};
  for (int k0 = 0; k0 < K; k0 += 16) {
    float4 a = *(const float4*)(A + (size_t)(m0 + lr) * K + k0 + lc);
    float4 b = *(const float4*)(B + (size_t)(n0 + lr) * K + k0 + lc);
    __syncthreads();
    As[lc+0][lr] = a.x; As[lc+1][lr] = a.y; As[lc+2][lr] = a.z; As[lc+3][lr] = a.w;
    Bs[lc+0][lr] = b.x; Bs[lc+1][lr] = b.y; Bs[lc+2][lr] = b.z; Bs[lc+3][lr] = b.w;
    __syncthreads();
    #pragma unroll
    for (int k = 0; k < 16; ++k) {
      const float4 a4 = *(const float4*)&As[k][ty*4];
      const float4 b4 = *(const float4*)&Bs[k][tx*4];
      const float aa[4] = {a4.x, a4.y, a4.z, a4.w};
      const float bb[4] = {b4.x, b4.y, b4.z, b4.w};
      #pragma unroll
      for (int u = 0; u < 4; ++u)
        #pragma unroll
        for (int v = 0; v < 4; ++v)
          acc[u][v] = fmaf(aa[u], bb[v], acc[u][v]);
    }
  }
  #pragma unroll
  for (int u = 0; u < 4; ++u) {
    const int m = m0 + ty*4 + u;
    float o[4];
    #pragma unroll
    for (int v = 0; v < 4; ++v) {
      float c = acc[u][v];
      if (bias) c += bias[n0 + tx*4 + v];
      if (relu) c = fmaxf(c, 0.0f);
      o[v] = c;
    }
    *(float4*)(C + (size_t)m * N + n0 + tx*4) = make_float4(o[0], o[1], o[2], o[3]);
  }
}

// ---------------------------------------------------------------------------
// Big fp32 GEMM: C[M,N] = A[M,K] @ B[N,K]^T.  Tile 128x128, BK=16,
// 256 threads, 8x8 acc/thread (cols split tx*4 and 64+tx*4 -> 2-way LDS
// aliasing only, which is free). M%128==0, N%128==0, K%16==0.
// ---------------------------------------------------------------------------
__global__ __launch_bounds__(256) void gemm128_bt(
    const float* __restrict__ A, const float* __restrict__ B,
    float* __restrict__ C, int M, int N, int K)
{
  __shared__ __align__(16) float As[16][136];
  __shared__ __align__(16) float Bs[16][136];
  const int m0 = blockIdx.x * 128;
  const int n0 = blockIdx.y * 128;
  const int t  = threadIdx.x;
  const int tx = t & 15, ty = t >> 4;
  const int sr = t >> 1;          // 0..127
  const int sc = (t & 1) * 8;     // 0 or 8
  float acc[8][8] = {};
  for (int k0 = 0; k0 < K; k0 += 16) {
    float4 a0 = *(const float4*)(A + (size_t)(m0 + sr) * K + k0 + sc);
    float4 a1 = *(const float4*)(A + (size_t)(m0 + sr) * K + k0 + sc + 4);
    float4 b0 = *(const float4*)(B + (size_t)(n0 + sr) * K + k0 + sc);
    float4 b1 = *(const float4*)(B + (size_t)(n0 + sr) * K + k0 + sc + 4);
    __syncthreads();
    As[sc+0][sr]=a0.x; As[sc+1][sr]=a0.y; As[sc+2][sr]=a0.z; As[sc+3][sr]=a0.w;
    As[sc+4][sr]=a1.x; As[sc+5][sr]=a1.y; As[sc+6][sr]=a1.z; As[sc+7][sr]=a1.w;
    Bs[sc+0][sr]=b0.x; Bs[sc+1][sr]=b0.y; Bs[sc+2][sr]=b0.z; Bs[sc+3][sr]=b0.w;
    Bs[sc+4][sr]=b1.x; Bs[sc+5][sr]=b1.y; Bs[sc+6][sr]=b1.z; Bs[sc+7][sr]=b1.w;
    __syncthreads();
    #pragma unroll
    for (int k = 0; k < 16; ++k) {
      const float4 av0 = *(const float4*)&As[k][ty*8];
      const float4 av1 = *(const float4*)&As[k][ty*8+4];
      const float4 bv0 = *(const float4*)&Bs[k][tx*4];
      const float4 bv1 = *(const float4*)&Bs[k][64+tx*4];
      const float aa[8] = {av0.x,av0.y,av0.z,av0.w,av1.x,av1.y,av1.z,av1.w};
      const float bb[8] = {bv0.x,bv0.y,bv0.z,bv0.w,bv1.x,bv1.y,bv1.z,bv1.w};
      #pragma unroll
      for (int u = 0; u < 8; ++u)
        #pragma unroll
        for (int v = 0; v < 8; ++v)
          acc[u][v] = fmaf(aa[u], bb[v], acc[u][v]);
    }
  }
  #pragma unroll
  for (int u = 0; u < 8; ++u) {
    const int m = m0 + ty*8 + u;
    *(float4*)(C + (size_t)m * N + n0 + tx*4)    = make_float4(acc[u][0],acc[u][1],acc[u][2],acc[u][3]);
    *(float4*)(C + (size_t)m * N + n0 + 64+tx*4) = make_float4(acc[u][4],acc[u][5],acc[u][6],acc[u][7]);
  }
}

// ---------------------------------------------------------------------------
// Split-K NN GEMM with exp fused into A staging:
// part[z] += exp(A[M,K]-m_row) @ B[K,N] over k-chunk z (chunk = K/gridDim.z).
// Tile 128x128, BK=16.  part layout: [z][M][N].
// ---------------------------------------------------------------------------
__global__ __launch_bounds__(256) void gemm128_nn_exp(
    const float* __restrict__ A, const float* __restrict__ B,
    const float* __restrict__ mArr, float* __restrict__ part,
    int M, int N, int K, int kchunk)
{
  __shared__ __align__(16) float As[16][136];
  __shared__ __align__(16) float Bs[16][136];
  const int m0 = blockIdx.x * 128;
  const int n0 = blockIdx.y * 128;
  const int kb = blockIdx.z * kchunk;
  const int t  = threadIdx.x;
  const int tx = t & 15, ty = t >> 4;
  const int sr = t >> 1;          // 0..127 (A rows)
  const int sc = (t & 1) * 8;     // 0 or 8
  const int br = t >> 4;          // 0..15 (B rows)
  const int bc = (t & 15) * 8;    // B cols
  const float mrow = mArr[m0 + sr];
  float acc[8][8] = {};
  for (int k0 = kb; k0 < kb + kchunk; k0 += 16) {
    float4 a0 = *(const float4*)(A + (size_t)(m0 + sr) * K + k0 + sc);
    float4 a1 = *(const float4*)(A + (size_t)(m0 + sr) * K + k0 + sc + 4);
    float4 b0 = *(const float4*)(B + (size_t)(k0 + br) * N + n0 + bc);
    float4 b1 = *(const float4*)(B + (size_t)(k0 + br) * N + n0 + bc + 4);
    __syncthreads();
    As[sc+0][sr]=__expf(a0.x-mrow); As[sc+1][sr]=__expf(a0.y-mrow);
    As[sc+2][sr]=__expf(a0.z-mrow); As[sc+3][sr]=__expf(a0.w-mrow);
    As[sc+4][sr]=__expf(a1.x-mrow); As[sc+5][sr]=__expf(a1.y-mrow);
    As[sc+6][sr]=__expf(a1.z-mrow); As[sc+7][sr]=__expf(a1.w-mrow);
    *(float4*)&Bs[br][bc]   = b0;
    *(float4*)&Bs[br][bc+4] = b1;
    __syncthreads();
    #pragma unroll
    for (int k = 0; k < 16; ++k) {
      const float4 av0 = *(const float4*)&As[k][ty*8];
      const float4 av1 = *(const float4*)&As[k][ty*8+4];
      const float4 bv0 = *(const float4*)&Bs[k][tx*4];
      const float4 bv1 = *(const float4*)&Bs[k][64+tx*4];
      const float aa[8] = {av0.x,av0.y,av0.z,av0.w,av1.x,av1.y,av1.z,av1.w};
      const float bb[8] = {bv0.x,bv0.y,bv0.z,bv0.w,bv1.x,bv1.y,bv1.z,bv1.w};
      #pragma unroll
      for (int u = 0; u < 8; ++u)
        #pragma unroll
        for (int v = 0; v < 8; ++v)
          acc[u][v] = fmaf(aa[u], bb[v], acc[u][v]);
    }
  }
  float* Cz = part + (size_t)blockIdx.z * M * N;
  #pragma unroll
  for (int u = 0; u < 8; ++u) {
    const int m = m0 + ty*8 + u;
    *(float4*)(Cz + (size_t)m * N + n0 + tx*4)    = make_float4(acc[u][0],acc[u][1],acc[u][2],acc[u][3]);
    *(float4*)(Cz + (size_t)m * N + n0 + 64+tx*4) = make_float4(acc[u][4],acc[u][5],acc[u][6],acc[u][7]);
  }
}

// reduce split-K partials: out[idx] = sum_z part[z*M*N + idx]
__global__ __launch_bounds__(256) void ksum(
    const float* __restrict__ part, float* __restrict__ out, int mn, int nz)
{
  int idx = blockIdx.x * 256 + threadIdx.x;
  if (idx >= mn) return;
  float s = 0.f;
  for (int z = 0; z < nz; ++z) s += part[(size_t)z * mn + idx];
  out[idx] = s;
}

// ---------------------------------------------------------------------------
// Per-column stats of S0T [BATCH, SLOTS]: base max, sum(exp(x-max)), top-16
// ---------------------------------------------------------------------------
__global__ __launch_bounds__(256) void col_stats(
    const float* __restrict__ S0T, float* __restrict__ m_base,
    float* __restrict__ se_base, float* __restrict__ t16v, int* __restrict__ t16i)
{
  const int i = blockIdx.x;
  const int t = threadIdx.x;
  const float* col = S0T + (size_t)i * SLOTS;
  float v[16]; int ix[16];
  #pragma unroll
  for (int q = 0; q < 16; ++q) { v[q] = -1e30f; ix[q] = 0x7fffffff; }
  const int base = t * (SLOTS / 256);
  for (int u = 0; u < 128; u += 4) {
    float4 x4 = *(const float4*)(col + base + u);
    float xs[4] = {x4.x, x4.y, x4.z, x4.w};
    #pragma unroll
    for (int e = 0; e < 4; ++e) {
      float cv = xs[e]; int ci = base + u + e;
      if (cv > v[15] || (cv == v[15] && ci < ix[15])) {
        #pragma unroll
        for (int q = 0; q < 16; ++q) {
          bool better = (cv > v[q]) || (cv == v[q] && ci < ix[q]);
          if (better) { float tv = v[q]; v[q] = cv; cv = tv;
                        int   ti = ix[q]; ix[q] = ci; ci = ti; }
        }
      }
    }
  }
  __shared__ float lv[4096];
  __shared__ int   li[4096];
  __shared__ float wbv[4]; __shared__ int wbi[4], wbp[4];
  __shared__ float bcastV;
  #pragma unroll
  for (int q = 0; q < 16; ++q) { lv[t*16+q] = v[q]; li[t*16+q] = ix[q]; }
  for (int r = 0; r < 16; ++r) {
    __syncthreads();
    float bv2 = -1e30f; int bi2 = 0x7fffffff, bp2 = -1;
    for (int q = 0; q < 16; ++q) {
      int p = t*16 + q;
      float xv = lv[p]; int xi = li[p];
      if (xv > bv2 || (xv == bv2 && xi < bi2)) { bv2 = xv; bi2 = xi; bp2 = p; }
    }
    for (int off = 32; off; off >>= 1) {
      float ov = __shfl_xor(bv2, off);
      int   oi = __shfl_xor(bi2, off);
      int   op = __shfl_xor(bp2, off);
      if (ov > bv2 || (ov == bv2 && oi < bi2)) { bv2 = ov; bi2 = oi; bp2 = op; }
    }
    if ((t & 63) == 0) { wbv[t>>6] = bv2; wbi[t>>6] = bi2; wbp[t>>6] = bp2; }
    __syncthreads();
    if (t == 0) {
      float fv = wbv[0]; int fi = wbi[0], fp = wbp[0];
      for (int w2 = 1; w2 < 4; ++w2)
        if (wbv[w2] > fv || (wbv[w2] == fv && wbi[w2] < fi)) {
          fv = wbv[w2]; fi = wbi[w2]; fp = wbp[w2];
        }
      t16v[i*16 + r] = fv; t16i[i*16 + r] = fi;
      lv[fp] = -1e30f; li[fp] = 0x7fffffff;
      if (r == 0) bcastV = fv;
    }
  }
  __syncthreads();
  const float m = bcastV;
  float s = 0.f;
  for (int u = 0; u < 128; u += 4) {
    float4 x4 = *(const float4*)(col + base + u);
    s += __expf(x4.x - m) + __expf(x4.y - m) + __expf(x4.z - m) + __expf(x4.w - m);
  }
  for (int off = 32; off; off >>= 1) s += __shfl_xor(s, off);
  __shared__ float ws2[4];
  if ((t & 63) == 0) ws2[t>>6] = s;
  __syncthreads();
  if (t == 0) { se_base[i] = ws2[0]+ws2[1]+ws2[2]+ws2[3]; m_base[i] = m; }
}

// ---------------------------------------------------------------------------
// Per-row top-16 of G[i, j<i] (value desc, j asc on ties). One wave per row.
// ---------------------------------------------------------------------------
__global__ __launch_bounds__(64) void gtop16(
    const float* __restrict__ G, float* __restrict__ gv16, int* __restrict__ gj16)
{
  const int i = blockIdx.x, lane = threadIdx.x;
  __shared__ float vals[BATCH];
  for (int q = lane; q < BATCH; q += 64) vals[q] = (q < i) ? G[(size_t)i*BATCH + q] : -1e30f;
  __syncthreads();
  for (int r = 0; r < 16; ++r) {
    float bv = -1e30f; int bj = 0x7fffffff;
    for (int q = lane; q < BATCH; q += 64) {
      float x = vals[q];
      if (x > bv || (x == bv && q < bj)) { bv = x; bj = q; }
    }
    #pragma unroll
    for (int off = 32; off; off >>= 1) {
      float ov = __shfl_xor(bv, off); int oj = __shfl_xor(bj, off);
      if (ov > bv || (ov == bv && oj < bj)) { bv = ov; bj = oj; }
    }
    if (lane == 0) {
      gv16[i*16 + r] = bv; gj16[i*16 + r] = (bj == 0x7fffffff) ? 0 : bj;
      if (bj != 0x7fffffff) vals[bj] = -1e30f;
    }
    __syncthreads();
  }
}

// ---------------------------------------------------------------------------
// Fast sequential phase: no wave-reduce on the critical path.
// Both candidate sets are precomputed descending top-16 lists; per step the
// winner is first-valid via one ballot + shfl.  Aliveness = uniform 4x64-bit
// mask; written set = LDS bitmap.  Full-scan fallbacks kept for safety.
// ---------------------------------------------------------------------------
__global__ __launch_bounds__(64) void seq_fast(
    const float* __restrict__ S0T, const float* __restrict__ G,
    const float* __restrict__ t16v, const int* __restrict__ t16i,
    const float* __restrict__ gv16, const int* __restrict__ gj16,
    int* __restrict__ slots)
{
  const int lane = threadIdx.x;
  __shared__ unsigned int bitmap[SLOTS/32];   // 4 KB
  __shared__ float sv[BATCH*16];              // 16 KB
  __shared__ int   si[BATCH*16];              // 16 KB
  __shared__ float gv[BATCH*16];              // 16 KB
  __shared__ int   gj[BATCH*16];              // 16 KB
  __shared__ int   slots_sh[BATCH];
  volatile unsigned int* vbm = bitmap;
  for (int q = lane; q < SLOTS/32; q += 64) bitmap[q] = 0u;
  for (int q = lane; q < BATCH*16; q += 64) {
    sv[q] = t16v[q]; si[q] = t16i[q]; gv[q] = gv16[q]; gj[q] = gj16[q];
  }
  __syncthreads();

  unsigned long long alive[4] = {0ull,0ull,0ull,0ull};
  int slotr0 = -1, slotr1 = -1, slotr2 = -1, slotr3 = -1;

  for (int i = 0; i < BATCH; ++i) {
    // ---- base candidate: first unwritten in descending top-16
    float myv = -1e30f; int myslot = 0; bool bvalid = false;
    if (lane < 16) {
      myv = sv[i*16 + lane]; myslot = si[i*16 + lane];
      bvalid = (((vbm[myslot >> 5] >> (myslot & 31)) & 1u) == 0u);
    }
    unsigned long long bb = __ballot(bvalid);
    // ---- override candidate: first alive in descending G top-16
    float ov = -1e30f; int oj = 0; bool ovalid = false;
    if (lane < 16) {
      ov = gv[i*16 + lane]; oj = gj[i*16 + lane];
      unsigned long long am = (oj < 64) ? alive[0] : (oj < 128) ? alive[1]
                             : (oj < 192) ? alive[2] : alive[3];
      ovalid = (ov > -1e29f) && (((am >> (oj & 63)) & 1ull) != 0ull);
    }
    unsigned long long ob = __ballot(ovalid);

    float bval; int bslot;
    if (bb != 0ull) {
      int bl = __ffsll((unsigned long long)bb) - 1;
      bval = __shfl(myv, bl); bslot = __shfl(myslot, bl);
    } else {
      // fallback: full scan of row i excluding written slots (~never)
      float fv = -1e30f; int fi = 0x7fffffff;
      for (int s = lane; s < SLOTS; s += 64) {
        if (((vbm[s >> 5] >> (s & 31)) & 1u) == 0u) {
          float x = S0T[(size_t)i*SLOTS + s];
          if (x > fv || (x == fv && s < fi)) { fv = x; fi = s; }
        }
      }
      #pragma unroll
      for (int off = 32; off; off >>= 1) {
        float ovv = __shfl_xor(fv, off); int oii = __shfl_xor(fi, off);
        if (ovv > fv || (ovv == fv && oii < fi)) { fv = ovv; fi = oii; }
      }
      bval = fv; bslot = fi;
    }

    float oval = -1e30f; int oslot = 0x7fffffff;
    if (ob != 0ull) {
      int ol = __ffsll((unsigned long long)ob) - 1;
      oval = __shfl(ov, ol);
      int ojw = __shfl(oj, ol);
      int r = ojw >> 6;
      int srg = (r == 0) ? slotr0 : (r == 1) ? slotr1 : (r == 2) ? slotr2 : slotr3;
      oslot = __shfl(srg, ojw & 63);
    } else if ((alive[0] | alive[1] | alive[2] | alive[3]) != 0ull) {
      // fallback: full reduce over alive G (~never)
      float fv = -1e30f; int fj = 0x7fffffff;
      #pragma unroll
      for (int r = 0; r < 4; ++r) {
        int j = lane + 64*r;
        if (j < i && ((alive[r] >> lane) & 1ull)) {
          float x = G[(size_t)i*BATCH + j];
          if (x > fv || (x == fv && j < fj)) { fv = x; fj = j; }
        }
      }
      #pragma unroll
      for (int off = 32; off; off >>= 1) {
        float ovv = __shfl_xor(fv, off); int ojj = __shfl_xor(fj, off);
        if (ovv > fv || (ovv == fv && ojj < fj)) { fv = ovv; fj = ojj; }
      }
      if (fj != 0x7fffffff) {
        oval = fv;
        int r = fj >> 6;
        int srg = (r == 0) ? slotr0 : (r == 1) ? slotr1 : (r == 2) ? slotr2 : slotr3;
        oslot = __shfl(srg, fj & 63);
      }
    }

    const bool owins = (oval > bval) || (oval == bval && oslot < bslot);
    const int sloti = owins ? oslot : bslot;

    // ---- commit: kill previous writer of sloti, install writer i
    unsigned long long kb0 = __ballot(slotr0 == sloti);
    unsigned long long kb1 = __ballot(slotr1 == sloti);
    unsigned long long kb2 = __ballot(slotr2 == sloti);
    unsigned long long kb3 = __ballot(slotr3 == sloti);
    alive[0] &= ~kb0; alive[1] &= ~kb1; alive[2] &= ~kb2; alive[3] &= ~kb3;
    const int r_new = i >> 6;
    if (lane == (i & 63)) {
      if (r_new == 0) slotr0 = sloti;
      else if (r_new == 1) slotr1 = sloti;
      else if (r_new == 2) slotr2 = sloti;
      else slotr3 = sloti;
    }
    alive[r_new] |= (1ull << (i & 63));
    if (lane == 0) {
      slots_sh[i] = sloti;
      vbm[sloti >> 5] = vbm[sloti >> 5] | (1u << (sloti & 31));
    }
    __builtin_amdgcn_wave_barrier();
  }
  for (int q = lane; q < BATCH; q += 64) slots[q] = slots_sh[q];
}

// ---------------------------------------------------------------------------
// nxt[j] = first step k>j that rewrites slots[j] (else INT_MAX).
// ---------------------------------------------------------------------------
__global__ __launch_bounds__(256) void nxt_kernel(
    const int* __restrict__ slots, int* __restrict__ nxt)
{
  __shared__ int sh[BATCH];
  const int j = threadIdx.x;
  sh[j] = slots[j];
  __syncthreads();
  const int sj = sh[j];
  int n = 0x7fffffff;
  for (int k = j + 1; k < BATCH; ++k)
    if (sh[k] == sj) { n = k; break; }
  nxt[j] = n;
}

// ---------------------------------------------------------------------------
// Parallel reconstruction of mi, Z, Cadd, Csub from slots/nxt.
// ---------------------------------------------------------------------------
__global__ __launch_bounds__(256) void coef_kernel(
    const float* __restrict__ S0T, const float* __restrict__ G,
    const int* __restrict__ slots, const int* __restrict__ nxt,
    const float* __restrict__ m_base, const float* __restrict__ se_base,
    float* __restrict__ mOut, float* __restrict__ Zout,
    float* __restrict__ Cadd, float* __restrict__ Csub)
{
  const int i = blockIdx.x, j = threadIdx.x;
  const bool alive = (j < i) && (nxt[j] >= i);
  const float g = alive ? G[(size_t)i*BATCH + j] : -1e30f;
  float bv = g;
  #pragma unroll
  for (int off = 32; off; off >>= 1) bv = fmaxf(bv, __shfl_xor(bv, off));
  __shared__ float red[4];
  if ((j & 63) == 0) red[j >> 6] = bv;
  __syncthreads();
  const float mb = m_base[i];
  const float mi = fmaxf(fmaxf(fmaxf(red[0], red[1]), fmaxf(red[2], red[3])), mb);
  const float sv = alive ? S0T[(size_t)i*SLOTS + slots[j]] : 0.f;
  const float ca = alive ? __expf(g - mi) : 0.f;
  const float cs = alive ? __expf(sv - mi) : 0.f;
  Cadd[(size_t)i*BATCH + j] = ca;
  Csub[(size_t)i*BATCH + j] = cs;
  float z = ca - cs;
  #pragma unroll
  for (int off = 32; off; off >>= 1) z += __shfl_xor(z, off);
  __syncthreads();
  if ((j & 63) == 0) red[j >> 6] = z;
  __syncthreads();
  if (j == 0) {
    mOut[i] = mi;
    Zout[i] = se_base[i] * __expf(mb - mi) + red[0] + red[1] + red[2] + red[3];
  }
}

// ---------------------------------------------------------------------------
// read_val = (read_num + Cadd@WV - Csub@mem_vals[slots]) / Z ; build merged.
// ---------------------------------------------------------------------------
__global__ __launch_bounds__(256) void readval_merge(
    const float* __restrict__ read_num, const float* __restrict__ Cadd,
    const float* __restrict__ Csub, const float* __restrict__ WVp,
    const float* __restrict__ mem_vals, const int* __restrict__ slots,
    const float* __restrict__ Zarr, const float* __restrict__ S_t,
    float* __restrict__ merged)
{
  const int i = blockIdx.x;
  const int t = threadIdx.x;
  merged[(size_t)i*1024 + t]        = S_t[(size_t)i*DIM + t];
  merged[(size_t)i*1024 + 256 + t]  = S_t[(size_t)i*DIM + 256 + t];
  float acc0 = read_num[(size_t)i*DIM + t];
  float acc1 = read_num[(size_t)i*DIM + 256 + t];
  for (int j = 0; j < BATCH; ++j) {
    float caj = Cadd[(size_t)i*BATCH + j];
    float csj = Csub[(size_t)i*BATCH + j];
    if (caj != 0.f || csj != 0.f) {
      int sj = slots[j];
      acc0 += caj * WVp[(size_t)j*DIM + t]       - csj * mem_vals[(size_t)sj*DIM + t];
      acc1 += caj * WVp[(size_t)j*DIM + 256 + t] - csj * mem_vals[(size_t)sj*DIM + 256 + t];
    }
  }
  const float invZ = 1.0f / Zarr[i];
  merged[(size_t)i*1024 + 512 + t] = acc0 * invZ;
  merged[(size_t)i*1024 + 768 + t] = acc1 * invZ;
}

// ---------------------------------------------------------------------------
extern "C" void kernel_launch(void* const* d_in, const int* in_sizes, int n_in,
                              void* d_out, int out_size, void* d_ws, size_t ws_size,
                              hipStream_t stream)
{
  (void)in_sizes; (void)n_in; (void)out_size; (void)ws_size;
  const float* S_t      = (const float*)d_in[0];
  const float* mem_keys = (const float*)d_in[1];
  const float* mem_vals = (const float*)d_in[2];
  const float* Wk       = (const float*)d_in[3];
  const float* bk       = (const float*)d_in[4];
  const float* Wv       = (const float*)d_in[5];
  const float* bv       = (const float*)d_in[6];
  const float* W1       = (const float*)d_in[7];
  const float* b1       = (const float*)d_in[8];
  const float* W2       = (const float*)d_in[9];
  const float* b2       = (const float*)d_in[10];
  float* out = (float*)d_out;

  float* ws = (float*)d_ws;
  float* Kp       = ws + 0;         // [256,512]
  float* WVp      = ws + 131072;    // [256,512]
  float* G        = ws + 262144;    // [256,256]
  float* S0T      = ws + 327680;    // [256,32768]
  float* m_base   = ws + 8716288;   // [256]
  float* se_base  = ws + 8716544;   // [256]
  float* t16v     = ws + 8716800;   // [256,16]
  int*   t16i     = (int*)(ws + 8720896);
  float* gv16     = ws + 8724992;   // [256,16]
  int*   gj16     = (int*)(ws + 8729088);
  int*   slots    = (int*)(ws + 8733184);
  int*   nxt      = (int*)(ws + 8733440);
  float* mOut     = ws + 8733696;
  float* Zout     = ws + 8733952;
  float* Cadd     = ws + 8734208;   // [256,256]
  float* Csub     = ws + 8799744;   // [256,256]
  float* read_num = ws + 8865280;   // [256,512]
  float* merged   = ws + 8996352;   // [256,1024]
  float* hid      = ws + 9258496;   // [256,2048]
  float* part     = ws + 9782784;   // [32][256,512] = 4.19M floats

  // phase 1: projections + gram + base scores
  gemm_bt<<<dim3(4, 8), dim3(256), 0, stream>>>(S_t, Wk, bk, Kp,  256, 512, 512, 0);
  gemm_bt<<<dim3(4, 8), dim3(256), 0, stream>>>(S_t, Wv, bv, WVp, 256, 512, 512, 0);
  gemm_bt<<<dim3(4, 4), dim3(256), 0, stream>>>(Kp,  Kp, nullptr, G, 256, 256, 512, 0);
  gemm128_bt<<<dim3(2, 256), dim3(256), 0, stream>>>(Kp, mem_keys, S0T, 256, 32768, 512);

  // phase 2: per-column stats, G top-16, fast sequential recurrence, coefs
  col_stats<<<dim3(256), dim3(256), 0, stream>>>(S0T, m_base, se_base, t16v, t16i);
  gtop16<<<dim3(256), dim3(64), 0, stream>>>(G, gv16, gj16);
  seq_fast<<<dim3(1), dim3(64), 0, stream>>>(S0T, G, t16v, t16i, gv16, gj16, slots);
  nxt_kernel<<<dim3(1), dim3(256), 0, stream>>>(slots, nxt);
  coef_kernel<<<dim3(256), dim3(256), 0, stream>>>(S0T, G, slots, nxt, m_base, se_base,
                                                   mOut, Zout, Cadd, Csub);

  // phase 3: batched read (exp fused into split-K GEMM) + corrections
  gemm128_nn_exp<<<dim3(2, 4, 32), dim3(256), 0, stream>>>(S0T, mem_vals, mOut, part,
                                                           256, 512, 32768, 1024);
  ksum<<<dim3(512), dim3(256), 0, stream>>>(part, read_num, 131072, 32);
  readval_merge<<<dim3(256), dim3(256), 0, stream>>>(read_num, Cadd, Csub, WVp,
                                                     mem_vals, slots, Zout, S_t, merged);

  // phase 4: MLP
  gemm_bt<<<dim3(4, 32), dim3(256), 0, stream>>>(merged, W1, b1, hid, 256, 2048, 1024, 1);
  gemm_bt<<<dim3(4, 8),  dim3(256), 0, stream>>>(hid,    W2, b2, out, 256, 512,  2048, 0);
}

// Round 4
// 1059.532 us; speedup vs baseline: 1.5283x; 1.0862x over previous
//
#include <hip/hip_runtime.h>
#include <cstdint>
#include <cstddef>

#define BATCH 256
#define DIM   512
#define HIDN  2048
#define SLOTS 32768

typedef __attribute__((ext_vector_type(8))) short short8;
typedef __attribute__((ext_vector_type(4))) float f32x4;

// ---------------------------------------------------------------------------
// bf16 split helpers (RNE)
// ---------------------------------------------------------------------------
__device__ __forceinline__ unsigned short bf_rne(float x) {
  unsigned int u = __float_as_uint(x);
  unsigned int r = (u + 0x7fffu + ((u >> 16) & 1u)) >> 16;
  return (unsigned short)r;
}
__device__ __forceinline__ unsigned short bf_split(float x, float& rem) {
  unsigned short h = bf_rne(x);
  rem = x - __uint_as_float(((unsigned int)h) << 16);
  return h;
}
__device__ __forceinline__ unsigned int pack2(unsigned short a, unsigned short b) {
  return (unsigned int)a | ((unsigned int)b << 16);
}

// ---------------------------------------------------------------------------
// Small tiled fp32 GEMM: C = act(A @ B^T + bias). Tile 64x64, TK=16.
// ---------------------------------------------------------------------------
__global__ __launch_bounds__(256) void gemm_bt(
    const float* __restrict__ A, const float* __restrict__ B,
    const float* __restrict__ bias, float* __restrict__ C,
    int M, int N, int K, int relu)
{
  __shared__ __align__(16) float As[16][68];
  __shared__ __align__(16) float Bs[16][68];
  const int m0 = blockIdx.x * 64;
  const int n0 = blockIdx.y * 64;
  const int t  = threadIdx.x;
  const int tx = t & 15, ty = t >> 4;
  const int lr = t >> 2;
  const int lc = (t & 3) * 4;
  float acc[4][4] = {};
  for (int k0 = 0; k0 < K; k0 += 16) {
    float4 a = *(const float4*)(A + (size_t)(m0 + lr) * K + k0 + lc);
    float4 b = *(const float4*)(B + (size_t)(n0 + lr) * K + k0 + lc);
    __syncthreads();
    As[lc+0][lr] = a.x; As[lc+1][lr] = a.y; As[lc+2][lr] = a.z; As[lc+3][lr] = a.w;
    Bs[lc+0][lr] = b.x; Bs[lc+1][lr] = b.y; Bs[lc+2][lr] = b.z; Bs[lc+3][lr] = b.w;
    __syncthreads();
    #pragma unroll
    for (int k = 0; k < 16; ++k) {
      const float4 a4 = *(const float4*)&As[k][ty*4];
      const float4 b4 = *(const float4*)&Bs[k][tx*4];
      const float aa[4] = {a4.x, a4.y, a4.z, a4.w};
      const float bb[4] = {b4.x, b4.y, b4.z, b4.w};
      #pragma unroll
      for (int u = 0; u < 4; ++u)
        #pragma unroll
        for (int v = 0; v < 4; ++v)
          acc[u][v] = fmaf(aa[u], bb[v], acc[u][v]);
    }
  }
  #pragma unroll
  for (int u = 0; u < 4; ++u) {
    const int m = m0 + ty*4 + u;
    float o[4];
    #pragma unroll
    for (int v = 0; v < 4; ++v) {
      float c = acc[u][v];
      if (bias) c += bias[n0 + tx*4 + v];
      if (relu) c = fmaxf(c, 0.0f);
      o[v] = c;
    }
    *(float4*)(C + (size_t)m * N + n0 + tx*4) = make_float4(o[0], o[1], o[2], o[3]);
  }
}

// ---------------------------------------------------------------------------
// fp32 -> bf16 hi/lo split (for the small A matrix Kp)
// ---------------------------------------------------------------------------
__global__ __launch_bounds__(256) void convert_hilo(
    const float* __restrict__ x, unsigned short* __restrict__ hi,
    unsigned short* __restrict__ lo, int n)
{
  int idx = (blockIdx.x * 256 + threadIdx.x) * 4;
  if (idx >= n) return;
  float4 v = *(const float4*)(x + idx);
  float r0, r1, r2, r3;
  unsigned short h0 = bf_split(v.x, r0), h1 = bf_split(v.y, r1);
  unsigned short h2 = bf_split(v.z, r2), h3 = bf_split(v.w, r3);
  *(uint2*)(hi + idx) = make_uint2(pack2(h0, h1), pack2(h2, h3));
  *(uint2*)(lo + idx) = make_uint2(pack2(bf_rne(r0), bf_rne(r1)),
                                   pack2(bf_rne(r2), bf_rne(r3)));
}

// ---------------------------------------------------------------------------
// MFMA GEMM with bf16 hi/lo compensation: C[M,N] = A @ B^T, fp32-accurate.
// A given pre-split (Ahi/Alo bf16, [M,K]); B fp32 [N,K] split in staging.
// Tile 128x128, BK=32, 4 waves (2x2 of 64x64), 16x16x32 MFMA, 3 mfma per
// fragment pair (hi*hi + lo*hi + hi*lo). LDS stride 40 (2-way alias = free).
// ---------------------------------------------------------------------------
#define LSTR 40
__global__ __launch_bounds__(256) void mfma_bt_hilo(
    const unsigned short* __restrict__ Ahi, const unsigned short* __restrict__ Alo,
    const float* __restrict__ B, float* __restrict__ C, int M, int N, int K)
{
  __shared__ __align__(16) unsigned short sAhi[128*LSTR];
  __shared__ __align__(16) unsigned short sAlo[128*LSTR];
  __shared__ __align__(16) unsigned short sBhi[128*LSTR];
  __shared__ __align__(16) unsigned short sBlo[128*LSTR];
  const int m0 = blockIdx.x * 128, n0 = blockIdx.y * 128;
  const int t = threadIdx.x;
  const int wave = t >> 6, lane = t & 63;
  const int wr = (wave >> 1) * 64, wc = (wave & 1) * 64;
  const int lrow = lane & 15, quad = lane >> 4;
  const int sr = t >> 1;           // 0..127
  const int sc = (t & 1) * 16;     // 0 or 16

  f32x4 acc[4][4];
  #pragma unroll
  for (int a = 0; a < 4; ++a)
    #pragma unroll
    for (int b = 0; b < 4; ++b)
      acc[a][b] = (f32x4){0.f, 0.f, 0.f, 0.f};

  for (int k0 = 0; k0 < K; k0 += 32) {
    const size_t aoff = (size_t)(m0 + sr) * K + k0 + sc;
    uint4 ah0 = *(const uint4*)(Ahi + aoff);
    uint4 ah1 = *(const uint4*)(Ahi + aoff + 8);
    uint4 al0 = *(const uint4*)(Alo + aoff);
    uint4 al1 = *(const uint4*)(Alo + aoff + 8);
    const float* bp = B + (size_t)(n0 + sr) * K + k0 + sc;
    float4 b0 = *(const float4*)(bp + 0);
    float4 b1 = *(const float4*)(bp + 4);
    float4 b2 = *(const float4*)(bp + 8);
    float4 b3 = *(const float4*)(bp + 12);
    float bx[16] = {b0.x,b0.y,b0.z,b0.w, b1.x,b1.y,b1.z,b1.w,
                    b2.x,b2.y,b2.z,b2.w, b3.x,b3.y,b3.z,b3.w};
    unsigned short bh[16], bl[16];
    #pragma unroll
    for (int e = 0; e < 16; ++e) {
      float rem; bh[e] = bf_split(bx[e], rem); bl[e] = bf_rne(rem);
    }
    __syncthreads();
    *(uint4*)&sAhi[sr*LSTR + sc]     = ah0;
    *(uint4*)&sAhi[sr*LSTR + sc + 8] = ah1;
    *(uint4*)&sAlo[sr*LSTR + sc]     = al0;
    *(uint4*)&sAlo[sr*LSTR + sc + 8] = al1;
    *(uint4*)&sBhi[sr*LSTR + sc] =
        make_uint4(pack2(bh[0],bh[1]), pack2(bh[2],bh[3]),
                   pack2(bh[4],bh[5]), pack2(bh[6],bh[7]));
    *(uint4*)&sBhi[sr*LSTR + sc + 8] =
        make_uint4(pack2(bh[8],bh[9]), pack2(bh[10],bh[11]),
                   pack2(bh[12],bh[13]), pack2(bh[14],bh[15]));
    *(uint4*)&sBlo[sr*LSTR + sc] =
        make_uint4(pack2(bl[0],bl[1]), pack2(bl[2],bl[3]),
                   pack2(bl[4],bl[5]), pack2(bl[6],bl[7]));
    *(uint4*)&sBlo[sr*LSTR + sc + 8] =
        make_uint4(pack2(bl[8],bl[9]), pack2(bl[10],bl[11]),
                   pack2(bl[12],bl[13]), pack2(bl[14],bl[15]));
    __syncthreads();

    short8 afh[4], afl[4], bfh[4], bfl[4];
    #pragma unroll
    for (int mt = 0; mt < 4; ++mt) {
      const int ar = wr + mt*16 + lrow;
      afh[mt] = *(const short8*)&sAhi[ar*LSTR + quad*8];
      afl[mt] = *(const short8*)&sAlo[ar*LSTR + quad*8];
    }
    #pragma unroll
    for (int nt = 0; nt < 4; ++nt) {
      const int br = wc + nt*16 + lrow;
      bfh[nt] = *(const short8*)&sBhi[br*LSTR + quad*8];
      bfl[nt] = *(const short8*)&sBlo[br*LSTR + quad*8];
    }
    #pragma unroll
    for (int mt = 0; mt < 4; ++mt)
      #pragma unroll
      for (int nt = 0; nt < 4; ++nt) {
        acc[mt][nt] = __builtin_amdgcn_mfma_f32_16x16x32_bf16(afh[mt], bfh[nt], acc[mt][nt], 0, 0, 0);
        acc[mt][nt] = __builtin_amdgcn_mfma_f32_16x16x32_bf16(afl[mt], bfh[nt], acc[mt][nt], 0, 0, 0);
        acc[mt][nt] = __builtin_amdgcn_mfma_f32_16x16x32_bf16(afh[mt], bfl[nt], acc[mt][nt], 0, 0, 0);
      }
  }
  // C/D layout: col = lane&15, row = quad*4 + reg  [m89-verified]
  #pragma unroll
  for (int mt = 0; mt < 4; ++mt)
    #pragma unroll
    for (int nt = 0; nt < 4; ++nt)
      #pragma unroll
      for (int reg = 0; reg < 4; ++reg) {
        const int m = m0 + wr + mt*16 + quad*4 + reg;
        const int n = n0 + wc + nt*16 + lrow;
        C[(size_t)m * N + n] = acc[mt][nt][reg];
      }
}

// ---------------------------------------------------------------------------
// Split-K NN GEMM with exp fused into A staging (fp32):
// part[z] += exp(A[M,K]-m_row) @ B[K,N] over k-chunk z.
// ---------------------------------------------------------------------------
__global__ __launch_bounds__(256) void gemm128_nn_exp(
    const float* __restrict__ A, const float* __restrict__ B,
    const float* __restrict__ mArr, float* __restrict__ part,
    int M, int N, int K, int kchunk)
{
  __shared__ __align__(16) float As[16][136];
  __shared__ __align__(16) float Bs[16][136];
  const int m0 = blockIdx.x * 128;
  const int n0 = blockIdx.y * 128;
  const int kb = blockIdx.z * kchunk;
  const int t  = threadIdx.x;
  const int tx = t & 15, ty = t >> 4;
  const int sr = t >> 1;
  const int sc = (t & 1) * 8;
  const int br = t >> 4;
  const int bc = (t & 15) * 8;
  const float mrow = mArr[m0 + sr];
  float acc[8][8] = {};
  for (int k0 = kb; k0 < kb + kchunk; k0 += 16) {
    float4 a0 = *(const float4*)(A + (size_t)(m0 + sr) * K + k0 + sc);
    float4 a1 = *(const float4*)(A + (size_t)(m0 + sr) * K + k0 + sc + 4);
    float4 b0 = *(const float4*)(B + (size_t)(k0 + br) * N + n0 + bc);
    float4 b1 = *(const float4*)(B + (size_t)(k0 + br) * N + n0 + bc + 4);
    __syncthreads();
    As[sc+0][sr]=__expf(a0.x-mrow); As[sc+1][sr]=__expf(a0.y-mrow);
    As[sc+2][sr]=__expf(a0.z-mrow); As[sc+3][sr]=__expf(a0.w-mrow);
    As[sc+4][sr]=__expf(a1.x-mrow); As[sc+5][sr]=__expf(a1.y-mrow);
    As[sc+6][sr]=__expf(a1.z-mrow); As[sc+7][sr]=__expf(a1.w-mrow);
    *(float4*)&Bs[br][bc]   = b0;
    *(float4*)&Bs[br][bc+4] = b1;
    __syncthreads();
    #pragma unroll
    for (int k = 0; k < 16; ++k) {
      const float4 av0 = *(const float4*)&As[k][ty*8];
      const float4 av1 = *(const float4*)&As[k][ty*8+4];
      const float4 bv0 = *(const float4*)&Bs[k][tx*4];
      const float4 bv1 = *(const float4*)&Bs[k][64+tx*4];
      const float aa[8] = {av0.x,av0.y,av0.z,av0.w,av1.x,av1.y,av1.z,av1.w};
      const float bb[8] = {bv0.x,bv0.y,bv0.z,bv0.w,bv1.x,bv1.y,bv1.z,bv1.w};
      #pragma unroll
      for (int u = 0; u < 8; ++u)
        #pragma unroll
        for (int v = 0; v < 8; ++v)
          acc[u][v] = fmaf(aa[u], bb[v], acc[u][v]);
    }
  }
  float* Cz = part + (size_t)blockIdx.z * M * N;
  #pragma unroll
  for (int u = 0; u < 8; ++u) {
    const int m = m0 + ty*8 + u;
    *(float4*)(Cz + (size_t)m * N + n0 + tx*4)    = make_float4(acc[u][0],acc[u][1],acc[u][2],acc[u][3]);
    *(float4*)(Cz + (size_t)m * N + n0 + 64+tx*4) = make_float4(acc[u][4],acc[u][5],acc[u][6],acc[u][7]);
  }
}

// reduce split-K partials
__global__ __launch_bounds__(256) void ksum(
    const float* __restrict__ part, float* __restrict__ out, int mn, int nz)
{
  int idx = blockIdx.x * 256 + threadIdx.x;
  if (idx >= mn) return;
  float s = 0.f;
  for (int z = 0; z < nz; ++z) s += part[(size_t)z * mn + idx];
  out[idx] = s;
}

// ---------------------------------------------------------------------------
// Per-column stats: register-resident tournament top-16 (no LDS table).
// Each thread: sorted-desc top-16 of its 128 contiguous elements in regs.
// 16 rounds: block-reduce the per-thread head elements; winner advances.
// ---------------------------------------------------------------------------
__global__ __launch_bounds__(256) void col_stats(
    const float* __restrict__ S0T, float* __restrict__ m_base,
    float* __restrict__ se_base, float* __restrict__ t16v, int* __restrict__ t16i)
{
  const int i = blockIdx.x;
  const int t = threadIdx.x;
  const float* col = S0T + (size_t)i * SLOTS;
  float v[16]; int ix[16];
  #pragma unroll
  for (int q = 0; q < 16; ++q) { v[q] = -1e30f; ix[q] = 0x7fffffff; }
  const int base = t * (SLOTS / 256);
  for (int u = 0; u < 128; u += 4) {
    float4 x4 = *(const float4*)(col + base + u);
    float xs[4] = {x4.x, x4.y, x4.z, x4.w};
    #pragma unroll
    for (int e = 0; e < 4; ++e) {
      float cv = xs[e]; int ci = base + u + e;
      if (cv > v[15] || (cv == v[15] && ci < ix[15])) {
        #pragma unroll
        for (int q = 0; q < 16; ++q) {
          bool better = (cv > v[q]) || (cv == v[q] && ci < ix[q]);
          if (better) { float tv = v[q]; v[q] = cv; cv = tv;
                        int   ti = ix[q]; ix[q] = ci; ci = ti; }
        }
      }
    }
  }
  __shared__ float redv[4]; __shared__ int redi[4];
  __shared__ float outv[16]; __shared__ int outi[16];
  int head = 0;
  float curv = v[0]; int curi = ix[0];
  for (int r = 0; r < 16; ++r) {
    float bv = curv; int bi = curi;
    #pragma unroll
    for (int off = 32; off; off >>= 1) {
      float ov = __shfl_xor(bv, off); int oi = __shfl_xor(bi, off);
      if (ov > bv || (ov == bv && oi < bi)) { bv = ov; bi = oi; }
    }
    if ((t & 63) == 0) { redv[t >> 6] = bv; redi[t >> 6] = bi; }
    __syncthreads();
    float fv = redv[0]; int fi = redi[0];
    #pragma unroll
    for (int w = 1; w < 4; ++w)
      if (redv[w] > fv || (redv[w] == fv && redi[w] < fi)) { fv = redv[w]; fi = redi[w]; }
    if (t == 0) { outv[r] = fv; outi[r] = fi; }
    if (curv == fv && curi == fi) {      // unique winner advances its head
      head++;
      float nv = -1e30f; int ni = 0x7fffffff;
      #pragma unroll
      for (int q = 0; q < 16; ++q)
        if (q == head) { nv = v[q]; ni = ix[q]; }
      curv = nv; curi = ni;
    }
    __syncthreads();
  }
  if (t < 16) { t16v[i*16 + t] = outv[t]; t16i[i*16 + t] = outi[t]; }
  const float m = outv[0];
  float s = 0.f;
  for (int u = 0; u < 128; u += 4) {
    float4 x4 = *(const float4*)(col + base + u);
    s += __expf(x4.x - m) + __expf(x4.y - m) + __expf(x4.z - m) + __expf(x4.w - m);
  }
  #pragma unroll
  for (int off = 32; off; off >>= 1) s += __shfl_xor(s, off);
  __shared__ float ws2[4];
  if ((t & 63) == 0) ws2[t >> 6] = s;
  __syncthreads();
  if (t == 0) { se_base[i] = ws2[0]+ws2[1]+ws2[2]+ws2[3]; m_base[i] = m; }
}

// ---------------------------------------------------------------------------
// Per-row top-16 of G[i, j<i]. One wave per row.
// ---------------------------------------------------------------------------
__global__ __launch_bounds__(64) void gtop16(
    const float* __restrict__ G, float* __restrict__ gv16, int* __restrict__ gj16)
{
  const int i = blockIdx.x, lane = threadIdx.x;
  __shared__ float vals[BATCH];
  for (int q = lane; q < BATCH; q += 64) vals[q] = (q < i) ? G[(size_t)i*BATCH + q] : -1e30f;
  __syncthreads();
  for (int r = 0; r < 16; ++r) {
    float bv = -1e30f; int bj = 0x7fffffff;
    for (int q = lane; q < BATCH; q += 64) {
      float x = vals[q];
      if (x > bv || (x == bv && q < bj)) { bv = x; bj = q; }
    }
    #pragma unroll
    for (int off = 32; off; off >>= 1) {
      float ov = __shfl_xor(bv, off); int oj = __shfl_xor(bj, off);
      if (ov > bv || (ov == bv && oj < bj)) { bv = ov; bj = oj; }
    }
    if (lane == 0) {
      gv16[i*16 + r] = bv; gj16[i*16 + r] = (bj == 0x7fffffff) ? 0 : bj;
      if (bj != 0x7fffffff) vals[bj] = -1e30f;
    }
    __syncthreads();
  }
}

// ---------------------------------------------------------------------------
// Fast sequential phase (unchanged from round 2).
// ---------------------------------------------------------------------------
__global__ __launch_bounds__(64) void seq_fast(
    const float* __restrict__ S0T, const float* __restrict__ G,
    const float* __restrict__ t16v, const int* __restrict__ t16i,
    const float* __restrict__ gv16, const int* __restrict__ gj16,
    int* __restrict__ slots)
{
  const int lane = threadIdx.x;
  __shared__ unsigned int bitmap[SLOTS/32];
  __shared__ float sv[BATCH*16];
  __shared__ int   si[BATCH*16];
  __shared__ float gv[BATCH*16];
  __shared__ int   gj[BATCH*16];
  __shared__ int   slots_sh[BATCH];
  volatile unsigned int* vbm = bitmap;
  for (int q = lane; q < SLOTS/32; q += 64) bitmap[q] = 0u;
  for (int q = lane; q < BATCH*16; q += 64) {
    sv[q] = t16v[q]; si[q] = t16i[q]; gv[q] = gv16[q]; gj[q] = gj16[q];
  }
  __syncthreads();

  unsigned long long alive[4] = {0ull,0ull,0ull,0ull};
  int slotr0 = -1, slotr1 = -1, slotr2 = -1, slotr3 = -1;

  for (int i = 0; i < BATCH; ++i) {
    float myv = -1e30f; int myslot = 0; bool bvalid = false;
    if (lane < 16) {
      myv = sv[i*16 + lane]; myslot = si[i*16 + lane];
      bvalid = (((vbm[myslot >> 5] >> (myslot & 31)) & 1u) == 0u);
    }
    unsigned long long bb = __ballot(bvalid);
    float ov = -1e30f; int oj = 0; bool ovalid = false;
    if (lane < 16) {
      ov = gv[i*16 + lane]; oj = gj[i*16 + lane];
      unsigned long long am = (oj < 64) ? alive[0] : (oj < 128) ? alive[1]
                             : (oj < 192) ? alive[2] : alive[3];
      ovalid = (ov > -1e29f) && (((am >> (oj & 63)) & 1ull) != 0ull);
    }
    unsigned long long ob = __ballot(ovalid);

    float bval; int bslot;
    if (bb != 0ull) {
      int bl = __ffsll((unsigned long long)bb) - 1;
      bval = __shfl(myv, bl); bslot = __shfl(myslot, bl);
    } else {
      float fv = -1e30f; int fi = 0x7fffffff;
      for (int s = lane; s < SLOTS; s += 64) {
        if (((vbm[s >> 5] >> (s & 31)) & 1u) == 0u) {
          float x = S0T[(size_t)i*SLOTS + s];
          if (x > fv || (x == fv && s < fi)) { fv = x; fi = s; }
        }
      }
      #pragma unroll
      for (int off = 32; off; off >>= 1) {
        float ovv = __shfl_xor(fv, off); int oii = __shfl_xor(fi, off);
        if (ovv > fv || (ovv == fv && oii < fi)) { fv = ovv; fi = oii; }
      }
      bval = fv; bslot = fi;
    }

    float oval = -1e30f; int oslot = 0x7fffffff;
    if (ob != 0ull) {
      int ol = __ffsll((unsigned long long)ob) - 1;
      oval = __shfl(ov, ol);
      int ojw = __shfl(oj, ol);
      int r = ojw >> 6;
      int srg = (r == 0) ? slotr0 : (r == 1) ? slotr1 : (r == 2) ? slotr2 : slotr3;
      oslot = __shfl(srg, ojw & 63);
    } else if ((alive[0] | alive[1] | alive[2] | alive[3]) != 0ull) {
      float fv = -1e30f; int fj = 0x7fffffff;
      #pragma unroll
      for (int r = 0; r < 4; ++r) {
        int j = lane + 64*r;
        if (j < i && ((alive[r] >> lane) & 1ull)) {
          float x = G[(size_t)i*BATCH + j];
          if (x > fv || (x == fv && j < fj)) { fv = x; fj = j; }
        }
      }
      #pragma unroll
      for (int off = 32; off; off >>= 1) {
        float ovv = __shfl_xor(fv, off); int ojj = __shfl_xor(fj, off);
        if (ovv > fv || (ovv == fv && ojj < fj)) { fv = ovv; fj = ojj; }
      }
      if (fj != 0x7fffffff) {
        oval = fv;
        int r = fj >> 6;
        int srg = (r == 0) ? slotr0 : (r == 1) ? slotr1 : (r == 2) ? slotr2 : slotr3;
        oslot = __shfl(srg, fj & 63);
      }
    }

    const bool owins = (oval > bval) || (oval == bval && oslot < bslot);
    const int sloti = owins ? oslot : bslot;

    unsigned long long kb0 = __ballot(slotr0 == sloti);
    unsigned long long kb1 = __ballot(slotr1 == sloti);
    unsigned long long kb2 = __ballot(slotr2 == sloti);
    unsigned long long kb3 = __ballot(slotr3 == sloti);
    alive[0] &= ~kb0; alive[1] &= ~kb1; alive[2] &= ~kb2; alive[3] &= ~kb3;
    const int r_new = i >> 6;
    if (lane == (i & 63)) {
      if (r_new == 0) slotr0 = sloti;
      else if (r_new == 1) slotr1 = sloti;
      else if (r_new == 2) slotr2 = sloti;
      else slotr3 = sloti;
    }
    alive[r_new] |= (1ull << (i & 63));
    if (lane == 0) {
      slots_sh[i] = sloti;
      vbm[sloti >> 5] = vbm[sloti >> 5] | (1u << (sloti & 31));
    }
    __builtin_amdgcn_wave_barrier();
  }
  for (int q = lane; q < BATCH; q += 64) slots[q] = slots_sh[q];
}

// ---------------------------------------------------------------------------
__global__ __launch_bounds__(256) void nxt_kernel(
    const int* __restrict__ slots, int* __restrict__ nxt)
{
  __shared__ int sh[BATCH];
  const int j = threadIdx.x;
  sh[j] = slots[j];
  __syncthreads();
  const int sj = sh[j];
  int n = 0x7fffffff;
  for (int k = j + 1; k < BATCH; ++k)
    if (sh[k] == sj) { n = k; break; }
  nxt[j] = n;
}

// ---------------------------------------------------------------------------
__global__ __launch_bounds__(256) void coef_kernel(
    const float* __restrict__ S0T, const float* __restrict__ G,
    const int* __restrict__ slots, const int* __restrict__ nxt,
    const float* __restrict__ m_base, const float* __restrict__ se_base,
    float* __restrict__ mOut, float* __restrict__ Zout,
    float* __restrict__ Cadd, float* __restrict__ Csub)
{
  const int i = blockIdx.x, j = threadIdx.x;
  const bool alive = (j < i) && (nxt[j] >= i);
  const float g = alive ? G[(size_t)i*BATCH + j] : -1e30f;
  float bv = g;
  #pragma unroll
  for (int off = 32; off; off >>= 1) bv = fmaxf(bv, __shfl_xor(bv, off));
  __shared__ float red[4];
  if ((j & 63) == 0) red[j >> 6] = bv;
  __syncthreads();
  const float mb = m_base[i];
  const float mi = fmaxf(fmaxf(fmaxf(red[0], red[1]), fmaxf(red[2], red[3])), mb);
  const float sv = alive ? S0T[(size_t)i*SLOTS + slots[j]] : 0.f;
  const float ca = alive ? __expf(g - mi) : 0.f;
  const float cs = alive ? __expf(sv - mi) : 0.f;
  Cadd[(size_t)i*BATCH + j] = ca;
  Csub[(size_t)i*BATCH + j] = cs;
  float z = ca - cs;
  #pragma unroll
  for (int off = 32; off; off >>= 1) z += __shfl_xor(z, off);
  __syncthreads();
  if ((j & 63) == 0) red[j >> 6] = z;
  __syncthreads();
  if (j == 0) {
    mOut[i] = mi;
    Zout[i] = se_base[i] * __expf(mb - mi) + red[0] + red[1] + red[2] + red[3];
  }
}

// ---------------------------------------------------------------------------
__global__ __launch_bounds__(256) void readval_merge(
    const float* __restrict__ read_num, const float* __restrict__ Cadd,
    const float* __restrict__ Csub, const float* __restrict__ WVp,
    const float* __restrict__ mem_vals, const int* __restrict__ slots,
    const float* __restrict__ Zarr, const float* __restrict__ S_t,
    float* __restrict__ merged)
{
  const int i = blockIdx.x;
  const int t = threadIdx.x;
  merged[(size_t)i*1024 + t]        = S_t[(size_t)i*DIM + t];
  merged[(size_t)i*1024 + 256 + t]  = S_t[(size_t)i*DIM + 256 + t];
  float acc0 = read_num[(size_t)i*DIM + t];
  float acc1 = read_num[(size_t)i*DIM + 256 + t];
  for (int j = 0; j < BATCH; ++j) {
    float caj = Cadd[(size_t)i*BATCH + j];
    float csj = Csub[(size_t)i*BATCH + j];
    if (caj != 0.f || csj != 0.f) {
      int sj = slots[j];
      acc0 += caj * WVp[(size_t)j*DIM + t]       - csj * mem_vals[(size_t)sj*DIM + t];
      acc1 += caj * WVp[(size_t)j*DIM + 256 + t] - csj * mem_vals[(size_t)sj*DIM + 256 + t];
    }
  }
  const float invZ = 1.0f / Zarr[i];
  merged[(size_t)i*1024 + 512 + t] = acc0 * invZ;
  merged[(size_t)i*1024 + 768 + t] = acc1 * invZ;
}

// ---------------------------------------------------------------------------
extern "C" void kernel_launch(void* const* d_in, const int* in_sizes, int n_in,
                              void* d_out, int out_size, void* d_ws, size_t ws_size,
                              hipStream_t stream)
{
  (void)in_sizes; (void)n_in; (void)out_size; (void)ws_size;
  const float* S_t      = (const float*)d_in[0];
  const float* mem_keys = (const float*)d_in[1];
  const float* mem_vals = (const float*)d_in[2];
  const float* Wk       = (const float*)d_in[3];
  const float* bk       = (const float*)d_in[4];
  const float* Wv       = (const float*)d_in[5];
  const float* bv       = (const float*)d_in[6];
  const float* W1       = (const float*)d_in[7];
  const float* b1       = (const float*)d_in[8];
  const float* W2       = (const float*)d_in[9];
  const float* b2       = (const float*)d_in[10];
  float* out = (float*)d_out;

  float* ws = (float*)d_ws;
  float* Kp       = ws + 0;         // [256,512]
  float* WVp      = ws + 131072;    // [256,512]
  float* G        = ws + 262144;    // [256,256]
  float* S0T      = ws + 327680;    // [256,32768]
  float* m_base   = ws + 8716288;   // [256]
  float* se_base  = ws + 8716544;   // [256]
  float* t16v     = ws + 8716800;   // [256,16]
  int*   t16i     = (int*)(ws + 8720896);
  float* gv16     = ws + 8724992;   // [256,16]
  int*   gj16     = (int*)(ws + 8729088);
  int*   slots    = (int*)(ws + 8733184);
  int*   nxt      = (int*)(ws + 8733440);
  float* mOut     = ws + 8733696;
  float* Zout     = ws + 8733952;
  float* Cadd     = ws + 8734208;   // [256,256]
  float* Csub     = ws + 8799744;   // [256,256]
  float* read_num = ws + 8865280;   // [256,512]
  float* merged   = ws + 8996352;   // [256,1024]
  float* hid      = ws + 9258496;   // [256,2048]
  float* part     = ws + 9782784;   // [32][256,512]
  unsigned short* Khi = (unsigned short*)(ws + 13977088);  // [256,512] bf16
  unsigned short* Klo = (unsigned short*)(ws + 14042624);  // [256,512] bf16

  // phase 1: projections + gram + base scores (scores via hi/lo MFMA)
  gemm_bt<<<dim3(4, 8), dim3(256), 0, stream>>>(S_t, Wk, bk, Kp,  256, 512, 512, 0);
  gemm_bt<<<dim3(4, 8), dim3(256), 0, stream>>>(S_t, Wv, bv, WVp, 256, 512, 512, 0);
  gemm_bt<<<dim3(4, 4), dim3(256), 0, stream>>>(Kp,  Kp, nullptr, G, 256, 256, 512, 0);
  convert_hilo<<<dim3(128), dim3(256), 0, stream>>>(Kp, Khi, Klo, 131072);
  mfma_bt_hilo<<<dim3(2, 256), dim3(256), 0, stream>>>(Khi, Klo, mem_keys, S0T,
                                                       256, 32768, 512);

  // phase 2: per-column stats, G top-16, sequential recurrence, coefs
  col_stats<<<dim3(256), dim3(256), 0, stream>>>(S0T, m_base, se_base, t16v, t16i);
  gtop16<<<dim3(256), dim3(64), 0, stream>>>(G, gv16, gj16);
  seq_fast<<<dim3(1), dim3(64), 0, stream>>>(S0T, G, t16v, t16i, gv16, gj16, slots);
  nxt_kernel<<<dim3(1), dim3(256), 0, stream>>>(slots, nxt);
  coef_kernel<<<dim3(256), dim3(256), 0, stream>>>(S0T, G, slots, nxt, m_base, se_base,
                                                   mOut, Zout, Cadd, Csub);

  // phase 3: batched read (exp fused into split-K GEMM) + corrections
  gemm128_nn_exp<<<dim3(2, 4, 32), dim3(256), 0, stream>>>(S0T, mem_vals, mOut, part,
                                                           256, 512, 32768, 1024);
  ksum<<<dim3(512), dim3(256), 0, stream>>>(part, read_num, 131072, 32);
  readval_merge<<<dim3(256), dim3(256), 0, stream>>>(read_num, Cadd, Csub, WVp,
                                                     mem_vals, slots, Zout, S_t, merged);

  // phase 4: MLP
  gemm_bt<<<dim3(4, 32), dim3(256), 0, stream>>>(merged, W1, b1, hid, 256, 2048, 1024, 1);
  gemm_bt<<<dim3(4, 8),  dim3(256), 0, stream>>>(hid,    W2, b2, out, 256, 512,  2048, 0);
}

// Round 6
// 971.216 us; speedup vs baseline: 1.6673x; 1.0909x over previous
//
#include <hip/hip_runtime.h>
#include <cstdint>
#include <cstddef>

#define BATCH 256
#define DIM   512
#define HIDN  2048
#define SLOTS 32768
#define NCHUNK 4
#define CHSZ  (SLOTS/NCHUNK)    // 8192

typedef __attribute__((ext_vector_type(8))) short short8;
typedef __attribute__((ext_vector_type(4))) float f32x4;

// ---------------------------------------------------------------------------
// bf16 split helpers (RNE)
// ---------------------------------------------------------------------------
__device__ __forceinline__ unsigned short bf_rne(float x) {
  unsigned int u = __float_as_uint(x);
  unsigned int r = (u + 0x7fffu + ((u >> 16) & 1u)) >> 16;
  return (unsigned short)r;
}
__device__ __forceinline__ unsigned short bf_split(float x, float& rem) {
  unsigned short h = bf_rne(x);
  rem = x - __uint_as_float(((unsigned int)h) << 16);
  return h;
}
__device__ __forceinline__ unsigned int pack2(unsigned short a, unsigned short b) {
  return (unsigned int)a | ((unsigned int)b << 16);
}

// ---------------------------------------------------------------------------
// Small tiled fp32 GEMM: C = act(A @ B^T + bias). Tile 64x64, TK=16.
// ---------------------------------------------------------------------------
__global__ __launch_bounds__(256) void gemm_bt(
    const float* __restrict__ A, const float* __restrict__ B,
    const float* __restrict__ bias, float* __restrict__ C,
    int M, int N, int K, int relu)
{
  __shared__ __align__(16) float As[16][68];
  __shared__ __align__(16) float Bs[16][68];
  const int m0 = blockIdx.x * 64;
  const int n0 = blockIdx.y * 64;
  const int t  = threadIdx.x;
  const int tx = t & 15, ty = t >> 4;
  const int lr = t >> 2;
  const int lc = (t & 3) * 4;
  float acc[4][4] = {};
  for (int k0 = 0; k0 < K; k0 += 16) {
    float4 a = *(const float4*)(A + (size_t)(m0 + lr) * K + k0 + lc);
    float4 b = *(const float4*)(B + (size_t)(n0 + lr) * K + k0 + lc);
    __syncthreads();
    As[lc+0][lr] = a.x; As[lc+1][lr] = a.y; As[lc+2][lr] = a.z; As[lc+3][lr] = a.w;
    Bs[lc+0][lr] = b.x; Bs[lc+1][lr] = b.y; Bs[lc+2][lr] = b.z; Bs[lc+3][lr] = b.w;
    __syncthreads();
    #pragma unroll
    for (int k = 0; k < 16; ++k) {
      const float4 a4 = *(const float4*)&As[k][ty*4];
      const float4 b4 = *(const float4*)&Bs[k][tx*4];
      const float aa[4] = {a4.x, a4.y, a4.z, a4.w};
      const float bb[4] = {b4.x, b4.y, b4.z, b4.w};
      #pragma unroll
      for (int u = 0; u < 4; ++u)
        #pragma unroll
        for (int v = 0; v < 4; ++v)
          acc[u][v] = fmaf(aa[u], bb[v], acc[u][v]);
    }
  }
  #pragma unroll
  for (int u = 0; u < 4; ++u) {
    const int m = m0 + ty*4 + u;
    float o[4];
    #pragma unroll
    for (int v = 0; v < 4; ++v) {
      float c = acc[u][v];
      if (bias) c += bias[n0 + tx*4 + v];
      if (relu) c = fmaxf(c, 0.0f);
      o[v] = c;
    }
    *(float4*)(C + (size_t)m * N + n0 + tx*4) = make_float4(o[0], o[1], o[2], o[3]);
  }
}

// ---------------------------------------------------------------------------
// fp32 -> bf16 hi/lo split
// ---------------------------------------------------------------------------
__global__ __launch_bounds__(256) void convert_hilo(
    const float* __restrict__ x, unsigned short* __restrict__ hi,
    unsigned short* __restrict__ lo, int n)
{
  int idx = (blockIdx.x * 256 + threadIdx.x) * 4;
  if (idx >= n) return;
  float4 v = *(const float4*)(x + idx);
  float r0, r1, r2, r3;
  unsigned short h0 = bf_split(v.x, r0), h1 = bf_split(v.y, r1);
  unsigned short h2 = bf_split(v.z, r2), h3 = bf_split(v.w, r3);
  *(uint2*)(hi + idx) = make_uint2(pack2(h0, h1), pack2(h2, h3));
  *(uint2*)(lo + idx) = make_uint2(pack2(bf_rne(r0), bf_rne(r1)),
                                   pack2(bf_rne(r2), bf_rne(r3)));
}

// ---------------------------------------------------------------------------
// MFMA GEMM with bf16 hi/lo compensation: C[M,N] = A @ B^T (fp32-accurate).
// ---------------------------------------------------------------------------
#define LSTR 40
__global__ __launch_bounds__(256) void mfma_bt_hilo(
    const unsigned short* __restrict__ Ahi, const unsigned short* __restrict__ Alo,
    const float* __restrict__ B, float* __restrict__ C, int M, int N, int K)
{
  __shared__ __align__(16) unsigned short sAhi[128*LSTR];
  __shared__ __align__(16) unsigned short sAlo[128*LSTR];
  __shared__ __align__(16) unsigned short sBhi[128*LSTR];
  __shared__ __align__(16) unsigned short sBlo[128*LSTR];
  const int m0 = blockIdx.x * 128, n0 = blockIdx.y * 128;
  const int t = threadIdx.x;
  const int wave = t >> 6, lane = t & 63;
  const int wr = (wave >> 1) * 64, wc = (wave & 1) * 64;
  const int lrow = lane & 15, quad = lane >> 4;
  const int sr = t >> 1;
  const int sc = (t & 1) * 16;

  f32x4 acc[4][4];
  #pragma unroll
  for (int a = 0; a < 4; ++a)
    #pragma unroll
    for (int b = 0; b < 4; ++b)
      acc[a][b] = (f32x4){0.f, 0.f, 0.f, 0.f};

  for (int k0 = 0; k0 < K; k0 += 32) {
    const size_t aoff = (size_t)(m0 + sr) * K + k0 + sc;
    uint4 ah0 = *(const uint4*)(Ahi + aoff);
    uint4 ah1 = *(const uint4*)(Ahi + aoff + 8);
    uint4 al0 = *(const uint4*)(Alo + aoff);
    uint4 al1 = *(const uint4*)(Alo + aoff + 8);
    const float* bp = B + (size_t)(n0 + sr) * K + k0 + sc;
    float4 b0 = *(const float4*)(bp + 0);
    float4 b1 = *(const float4*)(bp + 4);
    float4 b2 = *(const float4*)(bp + 8);
    float4 b3 = *(const float4*)(bp + 12);
    float bx[16] = {b0.x,b0.y,b0.z,b0.w, b1.x,b1.y,b1.z,b1.w,
                    b2.x,b2.y,b2.z,b2.w, b3.x,b3.y,b3.z,b3.w};
    unsigned short bh[16], bl[16];
    #pragma unroll
    for (int e = 0; e < 16; ++e) {
      float rem; bh[e] = bf_split(bx[e], rem); bl[e] = bf_rne(rem);
    }
    __syncthreads();
    *(uint4*)&sAhi[sr*LSTR + sc]     = ah0;
    *(uint4*)&sAhi[sr*LSTR + sc + 8] = ah1;
    *(uint4*)&sAlo[sr*LSTR + sc]     = al0;
    *(uint4*)&sAlo[sr*LSTR + sc + 8] = al1;
    *(uint4*)&sBhi[sr*LSTR + sc] =
        make_uint4(pack2(bh[0],bh[1]), pack2(bh[2],bh[3]),
                   pack2(bh[4],bh[5]), pack2(bh[6],bh[7]));
    *(uint4*)&sBhi[sr*LSTR + sc + 8] =
        make_uint4(pack2(bh[8],bh[9]), pack2(bh[10],bh[11]),
                   pack2(bh[12],bh[13]), pack2(bh[14],bh[15]));
    *(uint4*)&sBlo[sr*LSTR + sc] =
        make_uint4(pack2(bl[0],bl[1]), pack2(bl[2],bl[3]),
                   pack2(bl[4],bl[5]), pack2(bl[6],bl[7]));
    *(uint4*)&sBlo[sr*LSTR + sc + 8] =
        make_uint4(pack2(bl[8],bl[9]), pack2(bl[10],bl[11]),
                   pack2(bl[12],bl[13]), pack2(bl[14],bl[15]));
    __syncthreads();

    short8 afh[4], afl[4], bfh[4], bfl[4];
    #pragma unroll
    for (int mt = 0; mt < 4; ++mt) {
      const int ar = wr + mt*16 + lrow;
      afh[mt] = *(const short8*)&sAhi[ar*LSTR + quad*8];
      afl[mt] = *(const short8*)&sAlo[ar*LSTR + quad*8];
    }
    #pragma unroll
    for (int nt = 0; nt < 4; ++nt) {
      const int br = wc + nt*16 + lrow;
      bfh[nt] = *(const short8*)&sBhi[br*LSTR + quad*8];
      bfl[nt] = *(const short8*)&sBlo[br*LSTR + quad*8];
    }
    #pragma unroll
    for (int mt = 0; mt < 4; ++mt)
      #pragma unroll
      for (int nt = 0; nt < 4; ++nt) {
        acc[mt][nt] = __builtin_amdgcn_mfma_f32_16x16x32_bf16(afh[mt], bfh[nt], acc[mt][nt], 0, 0, 0);
        acc[mt][nt] = __builtin_amdgcn_mfma_f32_16x16x32_bf16(afl[mt], bfh[nt], acc[mt][nt], 0, 0, 0);
        acc[mt][nt] = __builtin_amdgcn_mfma_f32_16x16x32_bf16(afh[mt], bfl[nt], acc[mt][nt], 0, 0, 0);
      }
  }
  #pragma unroll
  for (int mt = 0; mt < 4; ++mt)
    #pragma unroll
    for (int nt = 0; nt < 4; ++nt)
      #pragma unroll
      for (int reg = 0; reg < 4; ++reg) {
        const int m = m0 + wr + mt*16 + quad*4 + reg;
        const int n = n0 + wc + nt*16 + lrow;
        C[(size_t)m * N + n] = acc[mt][nt][reg];
      }
}

// ---------------------------------------------------------------------------
// fp32 split-K NN exp-GEMM (round-4-proven path):
// part[z] = exp(A - m_row) @ B over k-chunk z.  Tile 128x128, BK=16.
// ---------------------------------------------------------------------------
__global__ __launch_bounds__(256) void gemm128_nn_exp(
    const float* __restrict__ A, const float* __restrict__ B,
    const float* __restrict__ mArr, float* __restrict__ part,
    int M, int N, int K, int kchunk)
{
  __shared__ __align__(16) float As[16][136];
  __shared__ __align__(16) float Bs[16][136];
  const int m0 = blockIdx.x * 128;
  const int n0 = blockIdx.y * 128;
  const int kb = blockIdx.z * kchunk;
  const int t  = threadIdx.x;
  const int tx = t & 15, ty = t >> 4;
  const int sr = t >> 1;
  const int sc = (t & 1) * 8;
  const int br = t >> 4;
  const int bc = (t & 15) * 8;
  const float mrow = mArr[m0 + sr];
  float acc[8][8] = {};
  for (int k0 = kb; k0 < kb + kchunk; k0 += 16) {
    float4 a0 = *(const float4*)(A + (size_t)(m0 + sr) * K + k0 + sc);
    float4 a1 = *(const float4*)(A + (size_t)(m0 + sr) * K + k0 + sc + 4);
    float4 b0 = *(const float4*)(B + (size_t)(k0 + br) * N + n0 + bc);
    float4 b1 = *(const float4*)(B + (size_t)(k0 + br) * N + n0 + bc + 4);
    __syncthreads();
    As[sc+0][sr]=__expf(a0.x-mrow); As[sc+1][sr]=__expf(a0.y-mrow);
    As[sc+2][sr]=__expf(a0.z-mrow); As[sc+3][sr]=__expf(a0.w-mrow);
    As[sc+4][sr]=__expf(a1.x-mrow); As[sc+5][sr]=__expf(a1.y-mrow);
    As[sc+6][sr]=__expf(a1.z-mrow); As[sc+7][sr]=__expf(a1.w-mrow);
    *(float4*)&Bs[br][bc]   = b0;
    *(float4*)&Bs[br][bc+4] = b1;
    __syncthreads();
    #pragma unroll
    for (int k = 0; k < 16; ++k) {
      const float4 av0 = *(const float4*)&As[k][ty*8];
      const float4 av1 = *(const float4*)&As[k][ty*8+4];
      const float4 bv0 = *(const float4*)&Bs[k][tx*4];
      const float4 bv1 = *(const float4*)&Bs[k][64+tx*4];
      const float aa[8] = {av0.x,av0.y,av0.z,av0.w,av1.x,av1.y,av1.z,av1.w};
      const float bb[8] = {bv0.x,bv0.y,bv0.z,bv0.w,bv1.x,bv1.y,bv1.z,bv1.w};
      #pragma unroll
      for (int u = 0; u < 8; ++u)
        #pragma unroll
        for (int v = 0; v < 8; ++v)
          acc[u][v] = fmaf(aa[u], bb[v], acc[u][v]);
    }
  }
  float* Cz = part + (size_t)blockIdx.z * M * N;
  #pragma unroll
  for (int u = 0; u < 8; ++u) {
    const int m = m0 + ty*8 + u;
    *(float4*)(Cz + (size_t)m * N + n0 + tx*4)    = make_float4(acc[u][0],acc[u][1],acc[u][2],acc[u][3]);
    *(float4*)(Cz + (size_t)m * N + n0 + 64+tx*4) = make_float4(acc[u][4],acc[u][5],acc[u][6],acc[u][7]);
  }
}

// reduce split-K partials
__global__ __launch_bounds__(256) void ksum(
    const float* __restrict__ part, float* __restrict__ out, int mn, int nz)
{
  int idx = blockIdx.x * 256 + threadIdx.x;
  if (idx >= mn) return;
  float s = 0.f;
  for (int z = 0; z < nz; ++z) s += part[(size_t)z * mn + idx];
  out[idx] = s;
}

// ---------------------------------------------------------------------------
// Per-chunk stats: top-16 + max + sumexp of one 8192-elem chunk of a row.
// All per-thread arrays statically indexed (registers). Grid (NCHUNK, BATCH).
// ---------------------------------------------------------------------------
__global__ __launch_bounds__(256) void col_chunk(
    const float* __restrict__ S0T, float* __restrict__ cmax,
    float* __restrict__ cse, float* __restrict__ c16v, int* __restrict__ c16i)
{
  const int ch = blockIdx.x, row = blockIdx.y;
  const int t = threadIdx.x;
  const float* col = S0T + (size_t)row * SLOTS + ch * CHSZ;
  const int base = t * (CHSZ / 256);     // 32 contiguous per thread
  float v[16]; int ix[16];
  #pragma unroll
  for (int q = 0; q < 16; ++q) { v[q] = -1e30f; ix[q] = 0x7fffffff; }
  #pragma unroll
  for (int u = 0; u < 32; u += 4) {
    float4 x4 = *(const float4*)(col + base + u);
    float xs[4] = {x4.x, x4.y, x4.z, x4.w};
    #pragma unroll
    for (int e = 0; e < 4; ++e) {
      float cv = xs[e]; int ci = ch * CHSZ + base + u + e;
      if (cv > v[15] || (cv == v[15] && ci < ix[15])) {
        #pragma unroll
        for (int q = 0; q < 16; ++q) {
          bool better = (cv > v[q]) || (cv == v[q] && ci < ix[q]);
          float tv = better ? v[q] : cv;  // static-index swap (cndmask)
          int   ti = better ? ix[q] : ci;
          v[q]  = better ? cv : v[q];
          ix[q] = better ? ci : ix[q];
          cv = tv; ci = ti;
        }
      }
    }
  }
  __shared__ float redv[4]; __shared__ int redi[4];
  __shared__ float outv[16]; __shared__ int outi[16];
  for (int r = 0; r < 16; ++r) {
    float bv = v[0]; int bi = ix[0];
    #pragma unroll
    for (int off = 32; off; off >>= 1) {
      float ov = __shfl_xor(bv, off); int oi = __shfl_xor(bi, off);
      if (ov > bv || (ov == bv && oi < bi)) { bv = ov; bi = oi; }
    }
    if ((t & 63) == 0) { redv[t >> 6] = bv; redi[t >> 6] = bi; }
    __syncthreads();
    float fv = redv[0]; int fi = redi[0];
    #pragma unroll
    for (int w = 1; w < 4; ++w)
      if (redv[w] > fv || (redv[w] == fv && redi[w] < fi)) { fv = redv[w]; fi = redi[w]; }
    if (t == 0) { outv[r] = fv; outi[r] = fi; }
    // winner advances via constant-indexed shift-down (keeps arrays in VGPRs)
    const bool adv = (v[0] == fv) && (ix[0] == fi);
    #pragma unroll
    for (int q = 0; q < 15; ++q) {
      v[q]  = adv ? v[q+1]  : v[q];
      ix[q] = adv ? ix[q+1] : ix[q];
    }
    v[15]  = adv ? -1e30f     : v[15];
    ix[15] = adv ? 0x7fffffff : ix[15];
    __syncthreads();
  }
  const int cidx = row * NCHUNK + ch;
  if (t < 16) { c16v[cidx*16 + t] = outv[t]; c16i[cidx*16 + t] = outi[t]; }
  const float m = outv[0];
  float s = 0.f;
  #pragma unroll
  for (int u = 0; u < 32; u += 4) {
    float4 x4 = *(const float4*)(col + base + u);
    s += __expf(x4.x - m) + __expf(x4.y - m) + __expf(x4.z - m) + __expf(x4.w - m);
  }
  #pragma unroll
  for (int off = 32; off; off >>= 1) s += __shfl_xor(s, off);
  __shared__ float ws2[4];
  if ((t & 63) == 0) ws2[t >> 6] = s;
  __syncthreads();
  if (t == 0) { cse[cidx] = ws2[0]+ws2[1]+ws2[2]+ws2[3]; cmax[cidx] = m; }
}

// ---------------------------------------------------------------------------
// Combine chunk stats: row max, rescaled sumexp, merged global top-16.
// One wave per row; lane = (chunk<<4) | pos candidate.
// ---------------------------------------------------------------------------
__global__ __launch_bounds__(64) void col_combine(
    const float* __restrict__ cmax, const float* __restrict__ cse,
    const float* __restrict__ c16v, const int* __restrict__ c16i,
    float* __restrict__ m_base, float* __restrict__ se_base,
    float* __restrict__ t16v, int* __restrict__ t16i)
{
  const int i = blockIdx.x, lane = threadIdx.x;
  float v = c16v[(size_t)i * 64 + lane];
  int   id = c16i[(size_t)i * 64 + lane];
  float m0 = cmax[i*4+0], m1 = cmax[i*4+1], m2 = cmax[i*4+2], m3 = cmax[i*4+3];
  const float m = fmaxf(fmaxf(m0, m1), fmaxf(m2, m3));
  const float se = cse[i*4+0]*__expf(m0-m) + cse[i*4+1]*__expf(m1-m)
                 + cse[i*4+2]*__expf(m2-m) + cse[i*4+3]*__expf(m3-m);
  bool dead = false;
  for (int r = 0; r < 16; ++r) {
    float bv = dead ? -1e30f : v;
    int   bi = dead ? 0x7fffffff : id;
    #pragma unroll
    for (int off = 32; off; off >>= 1) {
      float ov = __shfl_xor(bv, off); int oi = __shfl_xor(bi, off);
      if (ov > bv || (ov == bv && oi < bi)) { bv = ov; bi = oi; }
    }
    if (!dead && v == bv && id == bi) dead = true;
    if (lane == 0) { t16v[i*16 + r] = bv; t16i[i*16 + r] = bi; }
  }
  if (lane == 0) { m_base[i] = m; se_base[i] = se; }
}

// ---------------------------------------------------------------------------
// Per-row top-16 of G[i, j<i]. One wave per row.
// ---------------------------------------------------------------------------
__global__ __launch_bounds__(64) void gtop16(
    const float* __restrict__ G, float* __restrict__ gv16, int* __restrict__ gj16)
{
  const int i = blockIdx.x, lane = threadIdx.x;
  __shared__ float vals[BATCH];
  for (int q = lane; q < BATCH; q += 64) vals[q] = (q < i) ? G[(size_t)i*BATCH + q] : -1e30f;
  __syncthreads();
  for (int r = 0; r < 16; ++r) {
    float bv = -1e30f; int bj = 0x7fffffff;
    for (int q = lane; q < BATCH; q += 64) {
      float x = vals[q];
      if (x > bv || (x == bv && q < bj)) { bv = x; bj = q; }
    }
    #pragma unroll
    for (int off = 32; off; off >>= 1) {
      float ov = __shfl_xor(bv, off); int oj = __shfl_xor(bj, off);
      if (ov > bv || (ov == bv && oj < bj)) { bv = ov; bj = oj; }
    }
    if (lane == 0) {
      gv16[i*16 + r] = bv; gj16[i*16 + r] = (bj == 0x7fffffff) ? 0 : bj;
      if (bj != 0x7fffffff) vals[bj] = -1e30f;
    }
    __syncthreads();
  }
}

// ---------------------------------------------------------------------------
// Fast sequential phase (unchanged, round-3-proven).
// ---------------------------------------------------------------------------
__global__ __launch_bounds__(64) void seq_fast(
    const float* __restrict__ S0T, const float* __restrict__ G,
    const float* __restrict__ t16v, const int* __restrict__ t16i,
    const float* __restrict__ gv16, const int* __restrict__ gj16,
    int* __restrict__ slots)
{
  const int lane = threadIdx.x;
  __shared__ unsigned int bitmap[SLOTS/32];
  __shared__ float sv[BATCH*16];
  __shared__ int   si[BATCH*16];
  __shared__ float gv[BATCH*16];
  __shared__ int   gj[BATCH*16];
  __shared__ int   slots_sh[BATCH];
  volatile unsigned int* vbm = bitmap;
  for (int q = lane; q < SLOTS/32; q += 64) bitmap[q] = 0u;
  for (int q = lane; q < BATCH*16; q += 64) {
    sv[q] = t16v[q]; si[q] = t16i[q]; gv[q] = gv16[q]; gj[q] = gj16[q];
  }
  __syncthreads();

  unsigned long long alive[4] = {0ull,0ull,0ull,0ull};
  int slotr0 = -1, slotr1 = -1, slotr2 = -1, slotr3 = -1;

  for (int i = 0; i < BATCH; ++i) {
    float myv = -1e30f; int myslot = 0; bool bvalid = false;
    if (lane < 16) {
      myv = sv[i*16 + lane]; myslot = si[i*16 + lane];
      bvalid = (((vbm[myslot >> 5] >> (myslot & 31)) & 1u) == 0u);
    }
    unsigned long long bb = __ballot(bvalid);
    float ov = -1e30f; int oj = 0; bool ovalid = false;
    if (lane < 16) {
      ov = gv[i*16 + lane]; oj = gj[i*16 + lane];
      unsigned long long am = (oj < 64) ? alive[0] : (oj < 128) ? alive[1]
                             : (oj < 192) ? alive[2] : alive[3];
      ovalid = (ov > -1e29f) && (((am >> (oj & 63)) & 1ull) != 0ull);
    }
    unsigned long long ob = __ballot(ovalid);

    float bval; int bslot;
    if (bb != 0ull) {
      int bl = __ffsll((unsigned long long)bb) - 1;
      bval = __shfl(myv, bl); bslot = __shfl(myslot, bl);
    } else {
      float fv = -1e30f; int fi = 0x7fffffff;
      for (int s = lane; s < SLOTS; s += 64) {
        if (((vbm[s >> 5] >> (s & 31)) & 1u) == 0u) {
          float x = S0T[(size_t)i*SLOTS + s];
          if (x > fv || (x == fv && s < fi)) { fv = x; fi = s; }
        }
      }
      #pragma unroll
      for (int off = 32; off; off >>= 1) {
        float ovv = __shfl_xor(fv, off); int oii = __shfl_xor(fi, off);
        if (ovv > fv || (ovv == fv && oii < fi)) { fv = ovv; fi = oii; }
      }
      bval = fv; bslot = fi;
    }

    float oval = -1e30f; int oslot = 0x7fffffff;
    if (ob != 0ull) {
      int ol = __ffsll((unsigned long long)ob) - 1;
      oval = __shfl(ov, ol);
      int ojw = __shfl(oj, ol);
      int r = ojw >> 6;
      int srg = (r == 0) ? slotr0 : (r == 1) ? slotr1 : (r == 2) ? slotr2 : slotr3;
      oslot = __shfl(srg, ojw & 63);
    } else if ((alive[0] | alive[1] | alive[2] | alive[3]) != 0ull) {
      float fv = -1e30f; int fj = 0x7fffffff;
      #pragma unroll
      for (int r = 0; r < 4; ++r) {
        int j = lane + 64*r;
        if (j < i && ((alive[r] >> lane) & 1ull)) {
          float x = G[(size_t)i*BATCH + j];
          if (x > fv || (x == fv && j < fj)) { fv = x; fj = j; }
        }
      }
      #pragma unroll
      for (int off = 32; off; off >>= 1) {
        float ovv = __shfl_xor(fv, off); int ojj = __shfl_xor(fj, off);
        if (ovv > fv || (ovv == fv && ojj < fj)) { fv = ovv; fj = ojj; }
      }
      if (fj != 0x7fffffff) {
        oval = fv;
        int r = fj >> 6;
        int srg = (r == 0) ? slotr0 : (r == 1) ? slotr1 : (r == 2) ? slotr2 : slotr3;
        oslot = __shfl(srg, fj & 63);
      }
    }

    const bool owins = (oval > bval) || (oval == bval && oslot < bslot);
    const int sloti = owins ? oslot : bslot;

    unsigned long long kb0 = __ballot(slotr0 == sloti);
    unsigned long long kb1 = __ballot(slotr1 == sloti);
    unsigned long long kb2 = __ballot(slotr2 == sloti);
    unsigned long long kb3 = __ballot(slotr3 == sloti);
    alive[0] &= ~kb0; alive[1] &= ~kb1; alive[2] &= ~kb2; alive[3] &= ~kb3;
    const int r_new = i >> 6;
    if (lane == (i & 63)) {
      if (r_new == 0) slotr0 = sloti;
      else if (r_new == 1) slotr1 = sloti;
      else if (r_new == 2) slotr2 = sloti;
      else slotr3 = sloti;
    }
    alive[r_new] |= (1ull << (i & 63));
    if (lane == 0) {
      slots_sh[i] = sloti;
      vbm[sloti >> 5] = vbm[sloti >> 5] | (1u << (sloti & 31));
    }
    __builtin_amdgcn_wave_barrier();
  }
  for (int q = lane; q < BATCH; q += 64) slots[q] = slots_sh[q];
}

// ---------------------------------------------------------------------------
__global__ __launch_bounds__(256) void nxt_kernel(
    const int* __restrict__ slots, int* __restrict__ nxt)
{
  __shared__ int sh[BATCH];
  const int j = threadIdx.x;
  sh[j] = slots[j];
  __syncthreads();
  const int sj = sh[j];
  int n = 0x7fffffff;
  for (int k = j + 1; k < BATCH; ++k)
    if (sh[k] == sj) { n = k; break; }
  nxt[j] = n;
}

// ---------------------------------------------------------------------------
__global__ __launch_bounds__(256) void coef_kernel(
    const float* __restrict__ S0T, const float* __restrict__ G,
    const int* __restrict__ slots, const int* __restrict__ nxt,
    const float* __restrict__ m_base, const float* __restrict__ se_base,
    float* __restrict__ mOut, float* __restrict__ Zout,
    float* __restrict__ Cadd, float* __restrict__ Csub)
{
  const int i = blockIdx.x, j = threadIdx.x;
  const bool alive = (j < i) && (nxt[j] >= i);
  const float g = alive ? G[(size_t)i*BATCH + j] : -1e30f;
  float bv = g;
  #pragma unroll
  for (int off = 32; off; off >>= 1) bv = fmaxf(bv, __shfl_xor(bv, off));
  __shared__ float red[4];
  if ((j & 63) == 0) red[j >> 6] = bv;
  __syncthreads();
  const float mb = m_base[i];
  const float mi = fmaxf(fmaxf(fmaxf(red[0], red[1]), fmaxf(red[2], red[3])), mb);
  const float sv = alive ? S0T[(size_t)i*SLOTS + slots[j]] : 0.f;
  const float ca = alive ? __expf(g - mi) : 0.f;
  const float cs = alive ? __expf(sv - mi) : 0.f;
  Cadd[(size_t)i*BATCH + j] = ca;
  Csub[(size_t)i*BATCH + j] = cs;
  float z = ca - cs;
  #pragma unroll
  for (int off = 32; off; off >>= 1) z += __shfl_xor(z, off);
  __syncthreads();
  if ((j & 63) == 0) red[j >> 6] = z;
  __syncthreads();
  if (j == 0) {
    mOut[i] = mi;
    Zout[i] = se_base[i] * __expf(mb - mi) + red[0] + red[1] + red[2] + red[3];
  }
}

// ---------------------------------------------------------------------------
__global__ __launch_bounds__(256) void readval_merge(
    const float* __restrict__ read_num, const float* __restrict__ Cadd,
    const float* __restrict__ Csub, const float* __restrict__ WVp,
    const float* __restrict__ mem_vals, const int* __restrict__ slots,
    const float* __restrict__ Zarr, const float* __restrict__ S_t,
    float* __restrict__ merged)
{
  const int i = blockIdx.x;
  const int t = threadIdx.x;
  merged[(size_t)i*1024 + t]        = S_t[(size_t)i*DIM + t];
  merged[(size_t)i*1024 + 256 + t]  = S_t[(size_t)i*DIM + 256 + t];
  float acc0 = read_num[(size_t)i*DIM + t];
  float acc1 = read_num[(size_t)i*DIM + 256 + t];
  for (int j = 0; j < BATCH; ++j) {
    float caj = Cadd[(size_t)i*BATCH + j];
    float csj = Csub[(size_t)i*BATCH + j];
    if (caj != 0.f || csj != 0.f) {
      int sj = slots[j];
      acc0 += caj * WVp[(size_t)j*DIM + t]       - csj * mem_vals[(size_t)sj*DIM + t];
      acc1 += caj * WVp[(size_t)j*DIM + 256 + t] - csj * mem_vals[(size_t)sj*DIM + 256 + t];
    }
  }
  const float invZ = 1.0f / Zarr[i];
  merged[(size_t)i*1024 + 512 + t] = acc0 * invZ;
  merged[(size_t)i*1024 + 768 + t] = acc1 * invZ;
}

// ---------------------------------------------------------------------------
extern "C" void kernel_launch(void* const* d_in, const int* in_sizes, int n_in,
                              void* d_out, int out_size, void* d_ws, size_t ws_size,
                              hipStream_t stream)
{
  (void)in_sizes; (void)n_in; (void)out_size; (void)ws_size;
  const float* S_t      = (const float*)d_in[0];
  const float* mem_keys = (const float*)d_in[1];
  const float* mem_vals = (const float*)d_in[2];
  const float* Wk       = (const float*)d_in[3];
  const float* bk       = (const float*)d_in[4];
  const float* Wv       = (const float*)d_in[5];
  const float* bv       = (const float*)d_in[6];
  const float* W1       = (const float*)d_in[7];
  const float* b1       = (const float*)d_in[8];
  const float* W2       = (const float*)d_in[9];
  const float* b2       = (const float*)d_in[10];
  float* out = (float*)d_out;

  // Workspace layout — max offset 14108160 floats (56.4 MB), identical to the
  // round-4-proven footprint. col_chunk scratch lives at the HEAD of `part`
  // (consumed in phase 2, part written in phase 3 — order-safe).
  float* ws = (float*)d_ws;
  float* Kp       = ws + 0;         // [256,512]
  float* WVp      = ws + 131072;    // [256,512]
  float* G        = ws + 262144;    // [256,256]
  float* S0T      = ws + 327680;    // [256,32768]
  float* m_base   = ws + 8716288;   // [256]
  float* se_base  = ws + 8716544;   // [256]
  float* t16v     = ws + 8716800;   // [256,16]
  int*   t16i     = (int*)(ws + 8720896);
  float* gv16     = ws + 8724992;   // [256,16]
  int*   gj16     = (int*)(ws + 8729088);
  int*   slots    = (int*)(ws + 8733184);
  int*   nxt      = (int*)(ws + 8733440);
  float* mOut     = ws + 8733696;
  float* Zout     = ws + 8733952;
  float* Cadd     = ws + 8734208;   // [256,256]
  float* Csub     = ws + 8799744;   // [256,256]
  float* read_num = ws + 8865280;   // [256,512]
  float* merged   = ws + 8996352;   // [256,1024]
  float* hid      = ws + 9258496;   // [256,2048] ends 9782784
  float* part     = ws + 9782784;   // [32][256,512] ends 13977088
  // col_chunk scratch aliased onto head of part:
  float* cmaxb    = ws + 9782784;   // [256,4]
  float* cseb     = ws + 9783808;   // [256,4]
  float* c16vb    = ws + 9784832;   // [256,4,16]
  int*   c16ib    = (int*)(ws + 9801216);  // [256,4,16] ends 9817600 < 13977088
  unsigned short* Khi = (unsigned short*)(ws + 13977088);  // [256,512] bf16
  unsigned short* Klo = (unsigned short*)(ws + 14042624);  // [256,512] bf16, ends 14108160

  // phase 1: projections + gram + base scores (scores via hi/lo MFMA)
  gemm_bt<<<dim3(4, 8), dim3(256), 0, stream>>>(S_t, Wk, bk, Kp,  256, 512, 512, 0);
  gemm_bt<<<dim3(4, 8), dim3(256), 0, stream>>>(S_t, Wv, bv, WVp, 256, 512, 512, 0);
  gemm_bt<<<dim3(4, 4), dim3(256), 0, stream>>>(Kp,  Kp, nullptr, G, 256, 256, 512, 0);
  convert_hilo<<<dim3(128), dim3(256), 0, stream>>>(Kp, Khi, Klo, 131072);
  mfma_bt_hilo<<<dim3(2, 256), dim3(256), 0, stream>>>(Khi, Klo, mem_keys, S0T,
                                                       256, 32768, 512);

  // phase 2: chunked per-column stats + combine, G top-16, sequential, coefs
  col_chunk<<<dim3(NCHUNK, 256), dim3(256), 0, stream>>>(S0T, cmaxb, cseb, c16vb, c16ib);
  col_combine<<<dim3(256), dim3(64), 0, stream>>>(cmaxb, cseb, c16vb, c16ib,
                                                  m_base, se_base, t16v, t16i);
  gtop16<<<dim3(256), dim3(64), 0, stream>>>(G, gv16, gj16);
  seq_fast<<<dim3(1), dim3(64), 0, stream>>>(S0T, G, t16v, t16i, gv16, gj16, slots);
  nxt_kernel<<<dim3(1), dim3(256), 0, stream>>>(slots, nxt);
  coef_kernel<<<dim3(256), dim3(256), 0, stream>>>(S0T, G, slots, nxt, m_base, se_base,
                                                   mOut, Zout, Cadd, Csub);

  // phase 3: batched read (fp32 exp-GEMM, round-4-proven) + corrections
  gemm128_nn_exp<<<dim3(2, 4, 32), dim3(256), 0, stream>>>(S0T, mem_vals, mOut, part,
                                                           256, 512, 32768, 1024);
  ksum<<<dim3(512), dim3(256), 0, stream>>>(part, read_num, 131072, 32);
  readval_merge<<<dim3(256), dim3(256), 0, stream>>>(read_num, Cadd, Csub, WVp,
                                                     mem_vals, slots, Zout, S_t, merged);

  // phase 4: MLP
  gemm_bt<<<dim3(4, 32), dim3(256), 0, stream>>>(merged, W1, b1, hid, 256, 2048, 1024, 1);
  gemm_bt<<<dim3(4, 8),  dim3(256), 0, stream>>>(hid,    W2, b2, out, 256, 512,  2048, 0);
}